// Round 5
// baseline (437.530 us; speedup 1.0000x reference)
//
#include <hip/hip_runtime.h>
#include <math.h>

#define B_SZ   2
#define LSEQ   1024
#define DMODEL 1024
#define DINNER 2048
#define DSTATE 16
#define NTOK   (B_SZ * LSEQ)          // 2048 tokens
#define NSSM   (DINNER + 2 * DSTATE)  // 2080
#define CL     32                     // scan chunk length
#define NCH    (LSEQ / CL)            // 32 chunks
#define NC     (B_SZ * DINNER)        // 4096 channels

typedef unsigned short ushort;
typedef __attribute__((ext_vector_type(8))) ushort ushort8;
typedef __attribute__((ext_vector_type(8))) __bf16 bf16x8;
typedef __attribute__((ext_vector_type(4))) float floatx4;

__device__ __forceinline__ float softplus_f(float x) {
  return (x > 20.f) ? x : __logf(1.f + __expf(x));
}
__device__ __forceinline__ float silu_f(float x) {
  return x / (1.f + __expf(-x));
}
__device__ __forceinline__ float bf2f(ushort u) {
  return __uint_as_float(((unsigned)u) << 16);
}
__device__ __forceinline__ ushort f2bf(float f) {  // round-to-nearest-even
  unsigned u = __float_as_uint(f);
  return (ushort)((u + 0x7FFFu + ((u >> 16) & 1u)) >> 16);
}
// async global->LDS, 16B per lane; lds dst = wave-uniform base + lane*16
__device__ __forceinline__ void gld16(const ushort* g, ushort* l) {
  __builtin_amdgcn_global_load_lds(
      (const __attribute__((address_space(1))) void*)g,
      (__attribute__((address_space(3))) void*)l, 16, 0, 0);
}

// ---------------- RMSNorm → bf16 ----------------
__global__ __launch_bounds__(256) void rmsnorm_kernel(
    const float* __restrict__ x, const float* __restrict__ w,
    ushort* __restrict__ xn) {
  int row = blockIdx.x;
  const float* xrow = x + (size_t)row * DMODEL;
  float v[4];
  float ss = 0.f;
#pragma unroll
  for (int i = 0; i < 4; i++) {
    v[i] = xrow[threadIdx.x + 256 * i];
    ss += v[i] * v[i];
  }
  __shared__ float wsum[4];
  int lane = threadIdx.x & 63, wid = threadIdx.x >> 6;
#pragma unroll
  for (int off = 1; off < 64; off <<= 1) ss += __shfl_xor(ss, off);
  if (lane == 0) wsum[wid] = ss;
  __syncthreads();
  float tot = wsum[0] + wsum[1] + wsum[2] + wsum[3];
  float scale = rsqrtf(tot / (float)DMODEL + 1e-5f);
#pragma unroll
  for (int i = 0; i < 4; i++) {
    int j = threadIdx.x + 256 * i;
    xn[(size_t)row * DMODEL + j] = f2bf(v[i] * scale * w[j]);
  }
}

// ---------------- W [K][N] fp32 → W^T [N][K] bf16 (LDS-tiled) ----------------
__global__ __launch_bounds__(256) void transpose_w(
    const float* __restrict__ W, ushort* __restrict__ Wt, int K, int N) {
  __shared__ float tile[64][65];
  int n0 = blockIdx.x * 64, k0 = blockIdx.y * 64;
  int c = threadIdx.x & 63, rb = (threadIdx.x >> 6) << 4;
#pragma unroll
  for (int i = 0; i < 16; i++) {
    int k = k0 + rb + i;
    if (k < K && n0 + c < N) tile[rb + i][c] = W[(size_t)k * N + n0 + c];
  }
  __syncthreads();
#pragma unroll
  for (int i = 0; i < 16; i++) {
    int n = n0 + rb + i;
    if (n < N && k0 + c < K)
      Wt[(size_t)n * K + k0 + c] = f2bf(tile[c][rb + i]);
  }
}

// ---------------- bf16 MFMA GEMM: C[2048,N] = A[2048,K] @ Bt[N,K]^T ----------------
// 128x128 tile, BK=32, 4 waves, each wave 64x64 (4x4 of 16x16x32 mfma).
// Staging via global_load_lds width=16 (async, no VGPR round-trip).
// mode 0: C0=fp32 out (+addend, ldc=N)
// mode 1: n<2048 -> C0=bf16 xsraw; n>=2048 -> C1=bf16 silu() gate   (N=4096)
// mode 2: C0=bf16 ssm (ld NSSM); n>=2048 -> C1=fp32 bc[m][n-2048] (ld 32)
// mode 3: C0=fp32 softplus()  (ld DINNER)
__global__ __launch_bounds__(256) void gemm_mfma(
    const ushort* __restrict__ A, int lda,
    const ushort* __restrict__ Bt, int ldb,
    int N, int K, int mode,
    void* __restrict__ C0, void* __restrict__ C1,
    const float* __restrict__ addend) {
  __shared__ ushort As[128 * 32];  // 8 KB, row-major [m][k], 32 ushorts/row
  __shared__ ushort Bs[128 * 32];  // 8 KB, row-major [n][k]
  const int bm = blockIdx.y * 128, bn = blockIdx.x * 128;
  const int tid = threadIdx.x;
  const int wave = tid >> 6, lane = tid & 63;
  const int wm = (wave & 1) << 6, wn = (wave >> 1) << 6;
  const int lrow = lane & 15, quad = lane >> 4;

  // staging: each wave stages 32 A rows + 32 B rows per K-tile.
  // One gld16 covers 16 rows: lane -> row = lane>>2, kblock = lane&3 (16 B).
  const int sr = lane >> 2;          // 0..15
  const int sk = (lane & 3) << 3;    // ushort offset 0,8,16,24
  const int ar0 = bm + wave * 32 + sr;
  const int ar1 = ar0 + 16;
  const int br0 = min(bn + wave * 32 + sr, N - 1);       // clamp tail (global side only)
  const int br1 = min(bn + wave * 32 + 16 + sr, N - 1);
  const ushort* ga0 = A + (size_t)ar0 * lda + sk;
  const ushort* ga1 = A + (size_t)ar1 * lda + sk;
  const ushort* gb0 = Bt + (size_t)br0 * ldb + sk;
  const ushort* gb1 = Bt + (size_t)br1 * ldb + sk;
  ushort* la0 = As + (wave * 32) * 32;        // + lane*8 implicit in gld16
  ushort* la1 = As + (wave * 32 + 16) * 32;
  ushort* lb0 = Bs + (wave * 32) * 32;
  ushort* lb1 = Bs + (wave * 32 + 16) * 32;

  floatx4 acc[4][4];
#pragma unroll
  for (int i = 0; i < 4; i++)
#pragma unroll
    for (int j = 0; j < 4; j++) acc[i][j] = (floatx4){0.f, 0.f, 0.f, 0.f};

  const int nk = K >> 5;
  for (int kt = 0; kt < nk; kt++) {
    const int ko = kt << 5;
    __syncthreads();  // previous iter's frag reads done before overwrite
    gld16(ga0 + ko, la0);
    gld16(ga1 + ko, la1);
    gld16(gb0 + ko, lb0);
    gld16(gb1 + ko, lb1);
    __syncthreads();  // compiler drains vmcnt(0) before s_barrier
    bf16x8 af[4], bfr[4];
#pragma unroll
    for (int i = 0; i < 4; i++)
      af[i] = __builtin_bit_cast(bf16x8,
          *(const ushort8*)&As[(wm + i * 16 + lrow) * 32 + (quad << 3)]);
#pragma unroll
    for (int j = 0; j < 4; j++)
      bfr[j] = __builtin_bit_cast(bf16x8,
          *(const ushort8*)&Bs[(wn + j * 16 + lrow) * 32 + (quad << 3)]);
#pragma unroll
    for (int i = 0; i < 4; i++)
#pragma unroll
      for (int j = 0; j < 4; j++)
        acc[i][j] = __builtin_amdgcn_mfma_f32_16x16x32_bf16(
            af[i], bfr[j], acc[i][j], 0, 0, 0);
  }
  // epilogue: D row = quad*4+r, col = lane&15  [m89-verified]
  const int m0 = bm + wm, n0 = bn + wn, rq = quad << 2;
#pragma unroll
  for (int i = 0; i < 4; i++) {
#pragma unroll
    for (int j = 0; j < 4; j++) {
#pragma unroll
      for (int r = 0; r < 4; r++) {
        int m = m0 + i * 16 + rq + r;
        int n = n0 + j * 16 + lrow;
        if (n >= N) continue;
        float v = acc[i][j][r];
        if (mode == 0) {
          ((float*)C0)[(size_t)m * N + n] = v + addend[(size_t)m * N + n];
        } else if (mode == 1) {
          if (n < DINNER)
            ((ushort*)C0)[(size_t)m * DINNER + n] = f2bf(v);
          else
            ((ushort*)C1)[(size_t)m * DINNER + n - DINNER] = f2bf(silu_f(v));
        } else if (mode == 2) {
          ((ushort*)C0)[(size_t)m * NSSM + n] = f2bf(v);
          if (n >= DINNER)
            ((float*)C1)[(size_t)m * 32 + n - DINNER] = v;
        } else {
          ((float*)C0)[(size_t)m * DINNER + n] = softplus_f(v);
        }
      }
    }
  }
}

// ---------------- causal depthwise conv(4) + bias + silu (bf16 in/out) ----------------
__global__ __launch_bounds__(256) void conv_silu_kernel(
    const ushort* __restrict__ xsraw, const float* __restrict__ cw,
    const float* __restrict__ cb, ushort* __restrict__ xs) {
  int gid = blockIdx.x * 256 + threadIdx.x;
  int c = gid & (DINNER - 1);
  int t = gid >> 11;
  int l = t & (LSEQ - 1);
  float w0 = cw[c * 4 + 0], w1 = cw[c * 4 + 1], w2 = cw[c * 4 + 2], w3 = cw[c * 4 + 3];
  const ushort* col = xsraw + (size_t)t * DINNER + c;
  float acc = cb[c] + w3 * bf2f(col[0]);
  if (l >= 1) acc += w2 * bf2f(col[-DINNER]);
  if (l >= 2) acc += w1 * bf2f(col[-2 * DINNER]);
  if (l >= 3) acc += w0 * bf2f(col[-3 * DINNER]);
  xs[gid] = f2bf(silu_f(acc));
}

// ---------------- chunked selective scan (h[16]/thread, fp32 state) ----------------
__global__ __launch_bounds__(256) void scan_chunk1(
    const float* __restrict__ dt, const ushort* __restrict__ xs,
    const float* __restrict__ bc, const float* __restrict__ A_log,
    float* __restrict__ Bc, float* __restrict__ S) {
  int blk = blockIdx.x;
  int b = blk >> 8;
  int rem = blk & 255;
  int ch = rem >> 3;
  int dblk = rem & 7;
  int d = dblk * 256 + threadIdx.x;
  int c = b * DINNER + d;
  float a[DSTATE];
#pragma unroll
  for (int i = 0; i < 4; i++) {
    float4 v = *(const float4*)(A_log + (size_t)d * DSTATE + 4 * i);
    a[4 * i + 0] = -__expf(v.x);
    a[4 * i + 1] = -__expf(v.y);
    a[4 * i + 2] = -__expf(v.z);
    a[4 * i + 3] = -__expf(v.w);
  }
  float h[DSTATE] = {};
  float Ssum = 0.f;
  size_t t = (size_t)b * LSEQ + (size_t)ch * CL;
#pragma unroll 2
  for (int l = 0; l < CL; l++, t++) {
    float dtv = dt[t * DINNER + d];
    float dx = dtv * bf2f(xs[t * DINNER + d]);
    const float4* Bp = (const float4*)(bc + t * 32);
    float4 b0 = Bp[0], b1 = Bp[1], b2 = Bp[2], b3 = Bp[3];
    float bb[DSTATE] = {b0.x, b0.y, b0.z, b0.w, b1.x, b1.y, b1.z, b1.w,
                        b2.x, b2.y, b2.z, b2.w, b3.x, b3.y, b3.z, b3.w};
#pragma unroll
    for (int n = 0; n < DSTATE; n++)
      h[n] = __expf(a[n] * dtv) * h[n] + dx * bb[n];
    Ssum += dtv;
  }
  float4* outp = (float4*)(Bc + ((size_t)c * NCH + ch) * DSTATE);
  outp[0] = make_float4(h[0], h[1], h[2], h[3]);
  outp[1] = make_float4(h[4], h[5], h[6], h[7]);
  outp[2] = make_float4(h[8], h[9], h[10], h[11]);
  outp[3] = make_float4(h[12], h[13], h[14], h[15]);
  S[c * NCH + ch] = Ssum;
}

__global__ __launch_bounds__(256) void scan_combine(
    const float* __restrict__ A_log, const float* __restrict__ S,
    float* BcHin) {
  int gid = blockIdx.x * 256 + threadIdx.x;
  int c = gid >> 4, n = gid & 15;
  int d = c & (DINNER - 1);
  float a = -__expf(A_log[d * DSTATE + n]);
  float h = 0.f;
  size_t base = (size_t)c * (NCH * DSTATE) + n;
  for (int ch = 0; ch < NCH; ch++) {
    float bcv = BcHin[base + (size_t)ch * DSTATE];
    float decay = __expf(a * S[c * NCH + ch]);
    BcHin[base + (size_t)ch * DSTATE] = h;
    h = decay * h + bcv;
  }
}

__global__ __launch_bounds__(256) void scan_chunk2(
    const float* __restrict__ dt, const ushort* __restrict__ xs,
    const float* __restrict__ bc, const ushort* __restrict__ gate,
    const float* __restrict__ A_log, const float* __restrict__ hin,
    ushort* __restrict__ y) {
  int blk = blockIdx.x;
  int b = blk >> 8;
  int rem = blk & 255;
  int ch = rem >> 3;
  int dblk = rem & 7;
  int d = dblk * 256 + threadIdx.x;
  int c = b * DINNER + d;
  float a[DSTATE];
#pragma unroll
  for (int i = 0; i < 4; i++) {
    float4 v = *(const float4*)(A_log + (size_t)d * DSTATE + 4 * i);
    a[4 * i + 0] = -__expf(v.x);
    a[4 * i + 1] = -__expf(v.y);
    a[4 * i + 2] = -__expf(v.z);
    a[4 * i + 3] = -__expf(v.w);
  }
  float h[DSTATE];
  const float4* hi = (const float4*)(hin + ((size_t)c * NCH + ch) * DSTATE);
#pragma unroll
  for (int i = 0; i < 4; i++) {
    float4 v = hi[i];
    h[4 * i + 0] = v.x; h[4 * i + 1] = v.y; h[4 * i + 2] = v.z; h[4 * i + 3] = v.w;
  }
  size_t t = (size_t)b * LSEQ + (size_t)ch * CL;
#pragma unroll 2
  for (int l = 0; l < CL; l++, t++) {
    float dtv = dt[t * DINNER + d];
    float dx = dtv * bf2f(xs[t * DINNER + d]);
    const float4* Bp = (const float4*)(bc + t * 32);
    const float4* Cp = (const float4*)(bc + t * 32 + 16);
    float4 b0 = Bp[0], b1 = Bp[1], b2 = Bp[2], b3 = Bp[3];
    float4 c0 = Cp[0], c1 = Cp[1], c2 = Cp[2], c3 = Cp[3];
    float bb[DSTATE] = {b0.x, b0.y, b0.z, b0.w, b1.x, b1.y, b1.z, b1.w,
                        b2.x, b2.y, b2.z, b2.w, b3.x, b3.y, b3.z, b3.w};
    float cc[DSTATE] = {c0.x, c0.y, c0.z, c0.w, c1.x, c1.y, c1.z, c1.w,
                        c2.x, c2.y, c2.z, c2.w, c3.x, c3.y, c3.z, c3.w};
    float ysum = 0.f;
#pragma unroll
    for (int n = 0; n < DSTATE; n++) {
      h[n] = __expf(a[n] * dtv) * h[n] + dx * bb[n];
      ysum = fmaf(h[n], cc[n], ysum);
    }
    y[t * DINNER + d] = f2bf(ysum * bf2f(gate[t * DINNER + d]));
  }
}

extern "C" void kernel_launch(void* const* d_in, const int* in_sizes, int n_in,
                              void* d_out, int out_size, void* d_ws, size_t ws_size,
                              hipStream_t stream) {
  const float* x      = (const float*)d_in[0];
  const float* rms_w  = (const float*)d_in[1];
  const float* W_in   = (const float*)d_in[2];
  const float* conv_w = (const float*)d_in[3];
  const float* conv_b = (const float*)d_in[4];
  const float* W_x    = (const float*)d_in[5];
  const float* W_dt   = (const float*)d_in[6];
  const float* A_log  = (const float*)d_in[7];
  const float* W_out  = (const float*)d_in[8];
  float* out = (float*)d_out;

  // workspace layout, byte offsets (total 92,536,832 B = same as R1 footprint)
  char* w = (char*)d_ws;
  ushort* xnb   = (ushort*)(w + 0);         //  4 MiB  [2048,1024] bf16 (dead after GEMM1)
  ushort* xsraw = (ushort*)(w + 4194304);   //  8 MiB  [2048,2048] bf16 (dead after conv)
  ushort* gate  = (ushort*)(w + 12582912);  //  8 MiB  silu(res) bf16
  ushort* xsb   = (ushort*)(w + 20971520);  //  8 MiB  conv+silu out bf16
  ushort* ssmb  = (ushort*)(w + 29360128);  //  8.125 MiB [2048,2080] bf16
  float*  dtb   = (float*)(w + 37879808);   // 16 MiB  softplus(dt) fp32
  ushort* yb    = (ushort*)(w + 54657024);  //  8 MiB  scan out bf16
  ushort* WinT  = (ushort*)(w + 63045632);  //  8 MiB  [4096,1024]
  ushort* WxT   = (ushort*)(w + 71434240);  //  8.125 MiB [2080,2048]
  ushort* WdtT  = (ushort*)(w + 79953920);  //  8 MiB  [2048,2048]
  ushort* WoutT = (ushort*)(w + 88342528);  //  4 MiB  [1024,2048]
  // overlays of dead regions:
  float* bc = (float*)(w + 0);        // [2048,32] fp32 B|C (over xnb, 256 KiB) - written by GEMM2
  float* S  = (float*)(w + 262144);   // [NC,NCH] fp32 (over xnb, 512 KiB)
  float* Bc = (float*)(w + 4194304);  // [NC,NCH,16] fp32 (over xsraw, 8 MiB exactly)

  transpose_w<<<dim3(64, 16), 256, 0, stream>>>(W_in, WinT, DMODEL, 4096);
  transpose_w<<<dim3(33, 32), 256, 0, stream>>>(W_x, WxT, DINNER, NSSM);
  transpose_w<<<dim3(32, 32), 256, 0, stream>>>(W_dt, WdtT, DINNER, DINNER);
  transpose_w<<<dim3(16, 32), 256, 0, stream>>>(W_out, WoutT, DINNER, DMODEL);

  rmsnorm_kernel<<<NTOK, 256, 0, stream>>>(x, rms_w, xnb);
  // xr = xn @ W_in : split -> xsraw (bf16), gate = silu(res) (bf16)
  gemm_mfma<<<dim3(32, 16), 256, 0, stream>>>(
      xnb, DMODEL, WinT, DMODEL, 4096, DMODEL, 1, xsraw, gate, nullptr);
  conv_silu_kernel<<<(NTOK * DINNER) / 256, 256, 0, stream>>>(xsraw, conv_w, conv_b, xsb);
  // ssm = xs @ W_x : bf16 full + fp32 B/C columns compact
  gemm_mfma<<<dim3(17, 16), 256, 0, stream>>>(
      xsb, DINNER, WxT, DINNER, NSSM, DINNER, 2, ssmb, bc, nullptr);
  // dt = softplus(ssm[:, :2048] @ W_dt) fp32
  gemm_mfma<<<dim3(16, 16), 256, 0, stream>>>(
      ssmb, NSSM, WdtT, DINNER, DINNER, DINNER, 3, dtb, nullptr, nullptr);
  // chunked scan
  scan_chunk1<<<B_SZ * NCH * 8, 256, 0, stream>>>(dtb, xsb, bc, A_log, Bc, S);
  scan_combine<<<(NC * DSTATE) / 256, 256, 0, stream>>>(A_log, S, Bc);
  scan_chunk2<<<B_SZ * NCH * 8, 256, 0, stream>>>(dtb, xsb, bc, gate, A_log, Bc, yb);
  // out = y @ W_out + x
  gemm_mfma<<<dim3(8, 16), 256, 0, stream>>>(
      yb, DINNER, WoutT, DINNER, DMODEL, DINNER, 0, out, nullptr, x);
}

// Round 6
// 412.180 us; speedup vs baseline: 1.0615x; 1.0615x over previous
//
#include <hip/hip_runtime.h>
#include <math.h>

#define B_SZ   2
#define LSEQ   1024
#define DMODEL 1024
#define DINNER 2048
#define DSTATE 16
#define NTOK   (B_SZ * LSEQ)          // 2048 tokens
#define NSSM   (DINNER + 2 * DSTATE)  // 2080
#define CL     32                     // scan chunk length
#define NCH    (LSEQ / CL)            // 32 chunks
#define NC     (B_SZ * DINNER)        // 4096 channels

typedef unsigned short ushort;
typedef __attribute__((ext_vector_type(8))) ushort ushort8;
typedef __attribute__((ext_vector_type(8))) __bf16 bf16x8;
typedef __attribute__((ext_vector_type(4))) float floatx4;

__device__ __forceinline__ float softplus_f(float x) {
  return (x > 20.f) ? x : __logf(1.f + __expf(x));
}
__device__ __forceinline__ float silu_f(float x) {
  return x / (1.f + __expf(-x));
}
__device__ __forceinline__ float bf2f(ushort u) {
  return __uint_as_float(((unsigned)u) << 16);
}
__device__ __forceinline__ ushort f2bf(float f) {  // round-to-nearest-even
  unsigned u = __float_as_uint(f);
  return (ushort)((u + 0x7FFFu + ((u >> 16) & 1u)) >> 16);
}
// async global->LDS, 16B per lane; lds dst = wave-uniform base + lane*16
__device__ __forceinline__ void gld16(const ushort* g, ushort* l) {
  __builtin_amdgcn_global_load_lds(
      (const __attribute__((address_space(1))) void*)g,
      (__attribute__((address_space(3))) void*)l, 16, 0, 0);
}

// ---------------- RMSNorm → bf16 ----------------
__global__ __launch_bounds__(256) void rmsnorm_kernel(
    const float* __restrict__ x, const float* __restrict__ w,
    ushort* __restrict__ xn) {
  int row = blockIdx.x;
  const float* xrow = x + (size_t)row * DMODEL;
  float v[4];
  float ss = 0.f;
#pragma unroll
  for (int i = 0; i < 4; i++) {
    v[i] = xrow[threadIdx.x + 256 * i];
    ss += v[i] * v[i];
  }
  __shared__ float wsum[4];
  int lane = threadIdx.x & 63, wid = threadIdx.x >> 6;
#pragma unroll
  for (int off = 1; off < 64; off <<= 1) ss += __shfl_xor(ss, off);
  if (lane == 0) wsum[wid] = ss;
  __syncthreads();
  float tot = wsum[0] + wsum[1] + wsum[2] + wsum[3];
  float scale = rsqrtf(tot / (float)DMODEL + 1e-5f);
#pragma unroll
  for (int i = 0; i < 4; i++) {
    int j = threadIdx.x + 256 * i;
    xn[(size_t)row * DMODEL + j] = f2bf(v[i] * scale * w[j]);
  }
}

// ---------------- W [K][N] fp32 → W^T [N][K] bf16 (LDS-tiled) ----------------
__global__ __launch_bounds__(256) void transpose_w(
    const float* __restrict__ W, ushort* __restrict__ Wt, int K, int N) {
  __shared__ float tile[64][65];
  int n0 = blockIdx.x * 64, k0 = blockIdx.y * 64;
  int c = threadIdx.x & 63, rb = (threadIdx.x >> 6) << 4;
#pragma unroll
  for (int i = 0; i < 16; i++) {
    int k = k0 + rb + i;
    if (k < K && n0 + c < N) tile[rb + i][c] = W[(size_t)k * N + n0 + c];
  }
  __syncthreads();
#pragma unroll
  for (int i = 0; i < 16; i++) {
    int n = n0 + rb + i;
    if (n < N && k0 + c < K)
      Wt[(size_t)n * K + k0 + c] = f2bf(tile[c][rb + i]);
  }
}

// ---------------- bf16 MFMA GEMM: C[2048,N] = A[2048,K] @ Bt[N,K]^T ----------------
// 128x128 tile, BK=32, 4 waves, each wave 64x64 (4x4 of 16x16x32 mfma).
// Staging: global_load_lds width=16, DOUBLE-BUFFERED, one barrier/K-iter —
// next tile's async loads are in flight across the entire MFMA phase.
// mode 0: C0=fp32 out (+addend, ldc=N)
// mode 1: n<2048 -> C0=bf16 xsraw; n>=2048 -> C1=bf16 silu() gate   (N=4096)
// mode 2: C0=bf16 ssm (ld NSSM); n>=2048 -> C1=fp32 bc[m][n-2048] (ld 32)
// mode 3: C0=fp32 softplus()  (ld DINNER)
__global__ __launch_bounds__(256) void gemm_mfma(
    const ushort* __restrict__ A, int lda,
    const ushort* __restrict__ Bt, int ldb,
    int N, int K, int mode,
    void* __restrict__ C0, void* __restrict__ C1,
    const float* __restrict__ addend) {
  __shared__ ushort As[2 * 128 * 32];  // 16 KB double-buffered [m][k]
  __shared__ ushort Bs[2 * 128 * 32];  // 16 KB double-buffered [n][k]
  const int bm = blockIdx.y * 128, bn = blockIdx.x * 128;
  const int tid = threadIdx.x;
  const int wave = tid >> 6, lane = tid & 63;
  const int wm = (wave & 1) << 6, wn = (wave >> 1) << 6;
  const int lrow = lane & 15, quad = lane >> 4;

  // staging: each wave stages 32 A rows + 32 B rows per K-tile.
  // One gld16 covers 16 rows: lane -> row = lane>>2, kblock = lane&3 (16 B).
  const int sr = lane >> 2;          // 0..15
  const int sk = (lane & 3) << 3;    // ushort offset 0,8,16,24
  const int ar0 = bm + wave * 32 + sr;
  const int ar1 = ar0 + 16;
  const int br0 = min(bn + wave * 32 + sr, N - 1);       // clamp tail (global side only)
  const int br1 = min(bn + wave * 32 + 16 + sr, N - 1);
  const ushort* ga0 = A + (size_t)ar0 * lda + sk;
  const ushort* ga1 = A + (size_t)ar1 * lda + sk;
  const ushort* gb0 = Bt + (size_t)br0 * ldb + sk;
  const ushort* gb1 = Bt + (size_t)br1 * ldb + sk;
  ushort* la0 = As + (wave * 32) * 32;        // + lane*16B implicit in gld16
  ushort* la1 = As + (wave * 32 + 16) * 32;
  ushort* lb0 = Bs + (wave * 32) * 32;
  ushort* lb1 = Bs + (wave * 32 + 16) * 32;

  floatx4 acc[4][4];
#pragma unroll
  for (int i = 0; i < 4; i++)
#pragma unroll
    for (int j = 0; j < 4; j++) acc[i][j] = (floatx4){0.f, 0.f, 0.f, 0.f};

  const int nk = K >> 5;
  // prologue: tile 0 -> buffer 0
  gld16(ga0, la0);
  gld16(ga1, la1);
  gld16(gb0, lb0);
  gld16(gb1, lb1);
  for (int kt = 0; kt < nk; kt++) {
    __syncthreads();  // drains vmcnt -> buf[kt&1] ready; prev frag reads done
    if (kt + 1 < nk) {  // issue next tile into other buffer; lands during MFMA
      const int ko = (kt + 1) << 5;
      const int bo = ((kt + 1) & 1) << 12;  // 4096 ushorts per buffer
      gld16(ga0 + ko, la0 + bo);
      gld16(ga1 + ko, la1 + bo);
      gld16(gb0 + ko, lb0 + bo);
      gld16(gb1 + ko, lb1 + bo);
    }
    const int cb = (kt & 1) << 12;
    bf16x8 af[4], bfr[4];
#pragma unroll
    for (int i = 0; i < 4; i++)
      af[i] = __builtin_bit_cast(bf16x8,
          *(const ushort8*)&As[cb + (wm + i * 16 + lrow) * 32 + (quad << 3)]);
#pragma unroll
    for (int j = 0; j < 4; j++)
      bfr[j] = __builtin_bit_cast(bf16x8,
          *(const ushort8*)&Bs[cb + (wn + j * 16 + lrow) * 32 + (quad << 3)]);
#pragma unroll
    for (int i = 0; i < 4; i++)
#pragma unroll
      for (int j = 0; j < 4; j++)
        acc[i][j] = __builtin_amdgcn_mfma_f32_16x16x32_bf16(
            af[i], bfr[j], acc[i][j], 0, 0, 0);
  }
  // epilogue: D row = quad*4+r, col = lane&15  [m89-verified]
  const int m0 = bm + wm, n0 = bn + wn, rq = quad << 2;
#pragma unroll
  for (int i = 0; i < 4; i++) {
#pragma unroll
    for (int j = 0; j < 4; j++) {
#pragma unroll
      for (int r = 0; r < 4; r++) {
        int m = m0 + i * 16 + rq + r;
        int n = n0 + j * 16 + lrow;
        if (n >= N) continue;
        float v = acc[i][j][r];
        if (mode == 0) {
          ((float*)C0)[(size_t)m * N + n] = v + addend[(size_t)m * N + n];
        } else if (mode == 1) {
          if (n < DINNER)
            ((ushort*)C0)[(size_t)m * DINNER + n] = f2bf(v);
          else
            ((ushort*)C1)[(size_t)m * DINNER + n - DINNER] = f2bf(silu_f(v));
        } else if (mode == 2) {
          ((ushort*)C0)[(size_t)m * NSSM + n] = f2bf(v);
          if (n >= DINNER)
            ((float*)C1)[(size_t)m * 32 + n - DINNER] = v;
        } else {
          ((float*)C0)[(size_t)m * DINNER + n] = softplus_f(v);
        }
      }
    }
  }
}

// ---------------- causal depthwise conv(4) + bias + silu (bf16 in/out) ----------------
__global__ __launch_bounds__(256) void conv_silu_kernel(
    const ushort* __restrict__ xsraw, const float* __restrict__ cw,
    const float* __restrict__ cb, ushort* __restrict__ xs) {
  int gid = blockIdx.x * 256 + threadIdx.x;
  int c = gid & (DINNER - 1);
  int t = gid >> 11;
  int l = t & (LSEQ - 1);
  float w0 = cw[c * 4 + 0], w1 = cw[c * 4 + 1], w2 = cw[c * 4 + 2], w3 = cw[c * 4 + 3];
  const ushort* col = xsraw + (size_t)t * DINNER + c;
  float acc = cb[c] + w3 * bf2f(col[0]);
  if (l >= 1) acc += w2 * bf2f(col[-DINNER]);
  if (l >= 2) acc += w1 * bf2f(col[-2 * DINNER]);
  if (l >= 3) acc += w0 * bf2f(col[-3 * DINNER]);
  xs[gid] = f2bf(silu_f(acc));
}

// ---------------- chunked selective scan (h[16]/thread, fp32 state) ----------------
__global__ __launch_bounds__(256) void scan_chunk1(
    const float* __restrict__ dt, const ushort* __restrict__ xs,
    const float* __restrict__ bc, const float* __restrict__ A_log,
    float* __restrict__ Bc, float* __restrict__ S) {
  int blk = blockIdx.x;
  int b = blk >> 8;
  int rem = blk & 255;
  int ch = rem >> 3;
  int dblk = rem & 7;
  int d = dblk * 256 + threadIdx.x;
  int c = b * DINNER + d;
  float a[DSTATE];
#pragma unroll
  for (int i = 0; i < 4; i++) {
    float4 v = *(const float4*)(A_log + (size_t)d * DSTATE + 4 * i);
    a[4 * i + 0] = -__expf(v.x);
    a[4 * i + 1] = -__expf(v.y);
    a[4 * i + 2] = -__expf(v.z);
    a[4 * i + 3] = -__expf(v.w);
  }
  float h[DSTATE] = {};
  float Ssum = 0.f;
  size_t t = (size_t)b * LSEQ + (size_t)ch * CL;
#pragma unroll 2
  for (int l = 0; l < CL; l++, t++) {
    float dtv = dt[t * DINNER + d];
    float dx = dtv * bf2f(xs[t * DINNER + d]);
    const float4* Bp = (const float4*)(bc + t * 32);
    float4 b0 = Bp[0], b1 = Bp[1], b2 = Bp[2], b3 = Bp[3];
    float bb[DSTATE] = {b0.x, b0.y, b0.z, b0.w, b1.x, b1.y, b1.z, b1.w,
                        b2.x, b2.y, b2.z, b2.w, b3.x, b3.y, b3.z, b3.w};
#pragma unroll
    for (int n = 0; n < DSTATE; n++)
      h[n] = __expf(a[n] * dtv) * h[n] + dx * bb[n];
    Ssum += dtv;
  }
  float4* outp = (float4*)(Bc + ((size_t)c * NCH + ch) * DSTATE);
  outp[0] = make_float4(h[0], h[1], h[2], h[3]);
  outp[1] = make_float4(h[4], h[5], h[6], h[7]);
  outp[2] = make_float4(h[8], h[9], h[10], h[11]);
  outp[3] = make_float4(h[12], h[13], h[14], h[15]);
  S[c * NCH + ch] = Ssum;
}

__global__ __launch_bounds__(256) void scan_combine(
    const float* __restrict__ A_log, const float* __restrict__ S,
    float* BcHin) {
  int gid = blockIdx.x * 256 + threadIdx.x;
  int c = gid >> 4, n = gid & 15;
  int d = c & (DINNER - 1);
  float a = -__expf(A_log[d * DSTATE + n]);
  float h = 0.f;
  size_t base = (size_t)c * (NCH * DSTATE) + n;
  for (int ch = 0; ch < NCH; ch++) {
    float bcv = BcHin[base + (size_t)ch * DSTATE];
    float decay = __expf(a * S[c * NCH + ch]);
    BcHin[base + (size_t)ch * DSTATE] = h;
    h = decay * h + bcv;
  }
}

__global__ __launch_bounds__(256) void scan_chunk2(
    const float* __restrict__ dt, const ushort* __restrict__ xs,
    const float* __restrict__ bc, const ushort* __restrict__ gate,
    const float* __restrict__ A_log, const float* __restrict__ hin,
    ushort* __restrict__ y) {
  int blk = blockIdx.x;
  int b = blk >> 8;
  int rem = blk & 255;
  int ch = rem >> 3;
  int dblk = rem & 7;
  int d = dblk * 256 + threadIdx.x;
  int c = b * DINNER + d;
  float a[DSTATE];
#pragma unroll
  for (int i = 0; i < 4; i++) {
    float4 v = *(const float4*)(A_log + (size_t)d * DSTATE + 4 * i);
    a[4 * i + 0] = -__expf(v.x);
    a[4 * i + 1] = -__expf(v.y);
    a[4 * i + 2] = -__expf(v.z);
    a[4 * i + 3] = -__expf(v.w);
  }
  float h[DSTATE];
  const float4* hi = (const float4*)(hin + ((size_t)c * NCH + ch) * DSTATE);
#pragma unroll
  for (int i = 0; i < 4; i++) {
    float4 v = hi[i];
    h[4 * i + 0] = v.x; h[4 * i + 1] = v.y; h[4 * i + 2] = v.z; h[4 * i + 3] = v.w;
  }
  size_t t = (size_t)b * LSEQ + (size_t)ch * CL;
#pragma unroll 2
  for (int l = 0; l < CL; l++, t++) {
    float dtv = dt[t * DINNER + d];
    float dx = dtv * bf2f(xs[t * DINNER + d]);
    const float4* Bp = (const float4*)(bc + t * 32);
    const float4* Cp = (const float4*)(bc + t * 32 + 16);
    float4 b0 = Bp[0], b1 = Bp[1], b2 = Bp[2], b3 = Bp[3];
    float4 c0 = Cp[0], c1 = Cp[1], c2 = Cp[2], c3 = Cp[3];
    float bb[DSTATE] = {b0.x, b0.y, b0.z, b0.w, b1.x, b1.y, b1.z, b1.w,
                        b2.x, b2.y, b2.z, b2.w, b3.x, b3.y, b3.z, b3.w};
    float cc[DSTATE] = {c0.x, c0.y, c0.z, c0.w, c1.x, c1.y, c1.z, c1.w,
                        c2.x, c2.y, c2.z, c2.w, c3.x, c3.y, c3.z, c3.w};
    float ysum = 0.f;
#pragma unroll
    for (int n = 0; n < DSTATE; n++) {
      h[n] = __expf(a[n] * dtv) * h[n] + dx * bb[n];
      ysum = fmaf(h[n], cc[n], ysum);
    }
    y[t * DINNER + d] = f2bf(ysum * bf2f(gate[t * DINNER + d]));
  }
}

extern "C" void kernel_launch(void* const* d_in, const int* in_sizes, int n_in,
                              void* d_out, int out_size, void* d_ws, size_t ws_size,
                              hipStream_t stream) {
  const float* x      = (const float*)d_in[0];
  const float* rms_w  = (const float*)d_in[1];
  const float* W_in   = (const float*)d_in[2];
  const float* conv_w = (const float*)d_in[3];
  const float* conv_b = (const float*)d_in[4];
  const float* W_x    = (const float*)d_in[5];
  const float* W_dt   = (const float*)d_in[6];
  const float* A_log  = (const float*)d_in[7];
  const float* W_out  = (const float*)d_in[8];
  float* out = (float*)d_out;

  // workspace layout, byte offsets (total 92,536,832 B = same as R1 footprint)
  char* w = (char*)d_ws;
  ushort* xnb   = (ushort*)(w + 0);         //  4 MiB  [2048,1024] bf16 (dead after GEMM1)
  ushort* xsraw = (ushort*)(w + 4194304);   //  8 MiB  [2048,2048] bf16 (dead after conv)
  ushort* gate  = (ushort*)(w + 12582912);  //  8 MiB  silu(res) bf16
  ushort* xsb   = (ushort*)(w + 20971520);  //  8 MiB  conv+silu out bf16
  ushort* ssmb  = (ushort*)(w + 29360128);  //  8.125 MiB [2048,2080] bf16
  float*  dtb   = (float*)(w + 37879808);   // 16 MiB  softplus(dt) fp32
  ushort* yb    = (ushort*)(w + 54657024);  //  8 MiB  scan out bf16
  ushort* WinT  = (ushort*)(w + 63045632);  //  8 MiB  [4096,1024]
  ushort* WxT   = (ushort*)(w + 71434240);  //  8.125 MiB [2080,2048]
  ushort* WdtT  = (ushort*)(w + 79953920);  //  8 MiB  [2048,2048]
  ushort* WoutT = (ushort*)(w + 88342528);  //  4 MiB  [1024,2048]
  // overlays of dead regions:
  float* bc = (float*)(w + 0);        // [2048,32] fp32 B|C (over xnb, 256 KiB) - written by GEMM2
  float* S  = (float*)(w + 262144);   // [NC,NCH] fp32 (over xnb, 512 KiB)
  float* Bc = (float*)(w + 4194304);  // [NC,NCH,16] fp32 (over xsraw, 8 MiB exactly)

  transpose_w<<<dim3(64, 16), 256, 0, stream>>>(W_in, WinT, DMODEL, 4096);
  transpose_w<<<dim3(33, 32), 256, 0, stream>>>(W_x, WxT, DINNER, NSSM);
  transpose_w<<<dim3(32, 32), 256, 0, stream>>>(W_dt, WdtT, DINNER, DINNER);
  transpose_w<<<dim3(16, 32), 256, 0, stream>>>(W_out, WoutT, DINNER, DMODEL);

  rmsnorm_kernel<<<NTOK, 256, 0, stream>>>(x, rms_w, xnb);
  // xr = xn @ W_in : split -> xsraw (bf16), gate = silu(res) (bf16)
  gemm_mfma<<<dim3(32, 16), 256, 0, stream>>>(
      xnb, DMODEL, WinT, DMODEL, 4096, DMODEL, 1, xsraw, gate, nullptr);
  conv_silu_kernel<<<(NTOK * DINNER) / 256, 256, 0, stream>>>(xsraw, conv_w, conv_b, xsb);
  // ssm = xs @ W_x : bf16 full + fp32 B/C columns compact
  gemm_mfma<<<dim3(17, 16), 256, 0, stream>>>(
      xsb, DINNER, WxT, DINNER, NSSM, DINNER, 2, ssmb, bc, nullptr);
  // dt = softplus(ssm[:, :2048] @ W_dt) fp32
  gemm_mfma<<<dim3(16, 16), 256, 0, stream>>>(
      ssmb, NSSM, WdtT, DINNER, DINNER, DINNER, 3, dtb, nullptr, nullptr);
  // chunked scan
  scan_chunk1<<<B_SZ * NCH * 8, 256, 0, stream>>>(dtb, xsb, bc, A_log, Bc, S);
  scan_combine<<<(NC * DSTATE) / 256, 256, 0, stream>>>(A_log, S, Bc);
  scan_chunk2<<<B_SZ * NCH * 8, 256, 0, stream>>>(dtb, xsb, bc, gate, A_log, Bc, yb);
  // out = y @ W_out + x
  gemm_mfma<<<dim3(8, 16), 256, 0, stream>>>(
      yb, DINNER, WoutT, DINNER, DMODEL, DINNER, 0, out, nullptr, x);
}

// Round 7
// 384.870 us; speedup vs baseline: 1.1368x; 1.0710x over previous
//
#include <hip/hip_runtime.h>
#include <math.h>

#define B_SZ   2
#define LSEQ   1024
#define DMODEL 1024
#define DINNER 2048
#define DSTATE 16
#define NTOK   (B_SZ * LSEQ)          // 2048 tokens
#define NSSM   (DINNER + 2 * DSTATE)  // 2080
#define CL     32                     // scan chunk length
#define NCH    (LSEQ / CL)            // 32 chunks
#define NC     (B_SZ * DINNER)        // 4096 channels

typedef unsigned short ushort;
typedef __attribute__((ext_vector_type(8))) ushort ushort8;
typedef __attribute__((ext_vector_type(8))) __bf16 bf16x8;
typedef __attribute__((ext_vector_type(4))) float floatx4;

__device__ __forceinline__ float softplus_f(float x) {
  return (x > 20.f) ? x : __logf(1.f + __expf(x));
}
__device__ __forceinline__ float silu_f(float x) {
  return x / (1.f + __expf(-x));
}
__device__ __forceinline__ float bf2f(ushort u) {
  return __uint_as_float(((unsigned)u) << 16);
}
__device__ __forceinline__ ushort f2bf(float f) {  // round-to-nearest-even
  unsigned u = __float_as_uint(f);
  return (ushort)((u + 0x7FFFu + ((u >> 16) & 1u)) >> 16);
}

// ---------------- RMSNorm → bf16 ----------------
__global__ __launch_bounds__(256) void rmsnorm_kernel(
    const float* __restrict__ x, const float* __restrict__ w,
    ushort* __restrict__ xn) {
  int row = blockIdx.x;
  const float* xrow = x + (size_t)row * DMODEL;
  float v[4];
  float ss = 0.f;
#pragma unroll
  for (int i = 0; i < 4; i++) {
    v[i] = xrow[threadIdx.x + 256 * i];
    ss += v[i] * v[i];
  }
  __shared__ float wsum[4];
  int lane = threadIdx.x & 63, wid = threadIdx.x >> 6;
#pragma unroll
  for (int off = 1; off < 64; off <<= 1) ss += __shfl_xor(ss, off);
  if (lane == 0) wsum[wid] = ss;
  __syncthreads();
  float tot = wsum[0] + wsum[1] + wsum[2] + wsum[3];
  float scale = rsqrtf(tot / (float)DMODEL + 1e-5f);
#pragma unroll
  for (int i = 0; i < 4; i++) {
    int j = threadIdx.x + 256 * i;
    xn[(size_t)row * DMODEL + j] = f2bf(v[i] * scale * w[j]);
  }
}

// ---------------- W [K][N] fp32 → W^T [N][K] bf16 (LDS-tiled) ----------------
__global__ __launch_bounds__(256) void transpose_w(
    const float* __restrict__ W, ushort* __restrict__ Wt, int K, int N) {
  __shared__ float tile[64][65];
  int n0 = blockIdx.x * 64, k0 = blockIdx.y * 64;
  int c = threadIdx.x & 63, rb = (threadIdx.x >> 6) << 4;
#pragma unroll
  for (int i = 0; i < 16; i++) {
    int k = k0 + rb + i;
    if (k < K && n0 + c < N) tile[rb + i][c] = W[(size_t)k * N + n0 + c];
  }
  __syncthreads();
#pragma unroll
  for (int i = 0; i < 16; i++) {
    int n = n0 + rb + i;
    if (n < N && k0 + c < K)
      Wt[(size_t)n * K + k0 + c] = f2bf(tile[c][rb + i]);
  }
}

// ---------------- bf16 MFMA GEMM: C[2048,N] = A[2048,K] @ Bt[N,K]^T ----------------
// 128x128 tile, BK=32, 4 waves, each wave 64x64 (4x4 of 16x16x32 mfma).
// Register-prefetched staging + LDS double-buffer + ONE barrier per K-iter
// (VGPR-dest global loads don't force a vmcnt(0) drain at the barrier).
// XOR k-block swizzle: row r's logical 16B-block q sits at physical q^sw(r),
// sw(r) = (r ^ (r>>2)) & 3  -> conflict-free ds_read_b128 frag reads.
// mode 0: C0=fp32 out (+addend, ldc=N)
// mode 1: n<2048 -> C0=bf16 xsraw; n>=2048 -> C1=bf16 silu() gate   (N=4096)
// mode 2: C0=bf16 ssm (ld NSSM); n>=2048 -> C1=fp32 bc[m][n-2048] (ld 32)
// mode 3: C0=fp32 softplus()  (ld DINNER)
__global__ __launch_bounds__(256) void gemm_mfma(
    const ushort* __restrict__ A, int lda,
    const ushort* __restrict__ Bt, int ldb,
    int N, int K, int mode,
    void* __restrict__ C0, void* __restrict__ C1,
    const float* __restrict__ addend) {
  __shared__ ushort As[2 * 128 * 32];  // 16 KB double-buffered [m][k-swizzled]
  __shared__ ushort Bs[2 * 128 * 32];  // 16 KB double-buffered [n][k-swizzled]
  const int bm = blockIdx.y * 128, bn = blockIdx.x * 128;
  const int tid = threadIdx.x;
  const int wave = tid >> 6, lane = tid & 63;
  const int wm = (wave & 1) << 6, wn = (wave >> 1) << 6;
  const int lrow = lane & 15, quad = lane >> 4;

  // staging: thread t owns rows (t>>2) and (t>>2)+64, logical k-block t&3.
  const int sr = tid >> 2;                    // 0..63
  const int q  = tid & 3;                     // logical 16B k-block
  const int swr = (sr ^ (sr >> 2)) & 3;       // sw(sr) == sw(sr+64)
  const int pq = (q ^ swr) << 3;              // physical ushort offset in row
  const int br0 = min(bn + sr, N - 1);        // clamp tail (global side only)
  const int br1 = min(bn + sr + 64, N - 1);
  const ushort* ga0 = A + (size_t)(bm + sr) * lda + (q << 3);
  const ushort* ga1 = A + (size_t)(bm + sr + 64) * lda + (q << 3);
  const ushort* gb0 = Bt + (size_t)br0 * ldb + (q << 3);
  const ushort* gb1 = Bt + (size_t)br1 * ldb + (q << 3);

  floatx4 acc[4][4];
#pragma unroll
  for (int i = 0; i < 4; i++)
#pragma unroll
    for (int j = 0; j < 4; j++) acc[i][j] = (floatx4){0.f, 0.f, 0.f, 0.f};

  // frag-read swizzle: sw(m) depends only on lrow (wm, i*16 are 0 mod shift)
  const int swf = ((lrow ^ (lrow >> 2)) & 3);
  const int fq = ((quad ^ swf) << 3);

  const int nk = K >> 5;
  ushort8 ra0 = *(const ushort8*)ga0, ra1 = *(const ushort8*)ga1;
  ushort8 rb0 = *(const ushort8*)gb0, rb1 = *(const ushort8*)gb1;
  for (int kt = 0; kt < nk; kt++) {
    const int bo = (kt & 1) << 12;  // 4096 ushorts per buffer
    *(ushort8*)&As[bo + sr * 32 + pq] = ra0;
    *(ushort8*)&As[bo + (sr + 64) * 32 + pq] = ra1;
    *(ushort8*)&Bs[bo + sr * 32 + pq] = rb0;
    *(ushort8*)&Bs[bo + (sr + 64) * 32 + pq] = rb1;
    __syncthreads();
    if (kt + 1 < nk) {  // VGPR prefetch; lands any time before next iter's write
      const int ko = (kt + 1) << 5;
      ra0 = *(const ushort8*)(ga0 + ko);
      ra1 = *(const ushort8*)(ga1 + ko);
      rb0 = *(const ushort8*)(gb0 + ko);
      rb1 = *(const ushort8*)(gb1 + ko);
    }
    bf16x8 af[4], bfr[4];
#pragma unroll
    for (int i = 0; i < 4; i++)
      af[i] = __builtin_bit_cast(bf16x8,
          *(const ushort8*)&As[bo + (wm + i * 16 + lrow) * 32 + fq]);
#pragma unroll
    for (int j = 0; j < 4; j++)
      bfr[j] = __builtin_bit_cast(bf16x8,
          *(const ushort8*)&Bs[bo + (wn + j * 16 + lrow) * 32 + fq]);
#pragma unroll
    for (int i = 0; i < 4; i++)
#pragma unroll
      for (int j = 0; j < 4; j++)
        acc[i][j] = __builtin_amdgcn_mfma_f32_16x16x32_bf16(
            af[i], bfr[j], acc[i][j], 0, 0, 0);
  }
  // epilogue: D row = quad*4+r, col = lane&15  [m89-verified]
  const int m0 = bm + wm, n0 = bn + wn, rq = quad << 2;
#pragma unroll
  for (int i = 0; i < 4; i++) {
#pragma unroll
    for (int j = 0; j < 4; j++) {
#pragma unroll
      for (int r = 0; r < 4; r++) {
        int m = m0 + i * 16 + rq + r;
        int n = n0 + j * 16 + lrow;
        if (n >= N) continue;
        float v = acc[i][j][r];
        if (mode == 0) {
          ((float*)C0)[(size_t)m * N + n] = v + addend[(size_t)m * N + n];
        } else if (mode == 1) {
          if (n < DINNER)
            ((ushort*)C0)[(size_t)m * DINNER + n] = f2bf(v);
          else
            ((ushort*)C1)[(size_t)m * DINNER + n - DINNER] = f2bf(silu_f(v));
        } else if (mode == 2) {
          ((ushort*)C0)[(size_t)m * NSSM + n] = f2bf(v);
          if (n >= DINNER)
            ((float*)C1)[(size_t)m * 32 + n - DINNER] = v;
        } else {
          ((float*)C0)[(size_t)m * DINNER + n] = softplus_f(v);
        }
      }
    }
  }
}

// ---------------- causal depthwise conv(4) + bias + silu (bf16 in/out) ----------------
__global__ __launch_bounds__(256) void conv_silu_kernel(
    const ushort* __restrict__ xsraw, const float* __restrict__ cw,
    const float* __restrict__ cb, ushort* __restrict__ xs) {
  int gid = blockIdx.x * 256 + threadIdx.x;
  int c = gid & (DINNER - 1);
  int t = gid >> 11;
  int l = t & (LSEQ - 1);
  float w0 = cw[c * 4 + 0], w1 = cw[c * 4 + 1], w2 = cw[c * 4 + 2], w3 = cw[c * 4 + 3];
  const ushort* col = xsraw + (size_t)t * DINNER + c;
  float acc = cb[c] + w3 * bf2f(col[0]);
  if (l >= 1) acc += w2 * bf2f(col[-DINNER]);
  if (l >= 2) acc += w1 * bf2f(col[-2 * DINNER]);
  if (l >= 3) acc += w0 * bf2f(col[-3 * DINNER]);
  xs[gid] = f2bf(silu_f(acc));
}

// ---------------- chunked selective scan (h[16]/thread, fp32 state) ----------------
__global__ __launch_bounds__(256) void scan_chunk1(
    const float* __restrict__ dt, const ushort* __restrict__ xs,
    const float* __restrict__ bc, const float* __restrict__ A_log,
    float* __restrict__ Bc, float* __restrict__ S) {
  int blk = blockIdx.x;
  int b = blk >> 8;
  int rem = blk & 255;
  int ch = rem >> 3;
  int dblk = rem & 7;
  int d = dblk * 256 + threadIdx.x;
  int c = b * DINNER + d;
  float a[DSTATE];
#pragma unroll
  for (int i = 0; i < 4; i++) {
    float4 v = *(const float4*)(A_log + (size_t)d * DSTATE + 4 * i);
    a[4 * i + 0] = -__expf(v.x);
    a[4 * i + 1] = -__expf(v.y);
    a[4 * i + 2] = -__expf(v.z);
    a[4 * i + 3] = -__expf(v.w);
  }
  float h[DSTATE] = {};
  float Ssum = 0.f;
  size_t t = (size_t)b * LSEQ + (size_t)ch * CL;
#pragma unroll 2
  for (int l = 0; l < CL; l++, t++) {
    float dtv = dt[t * DINNER + d];
    float dx = dtv * bf2f(xs[t * DINNER + d]);
    const float4* Bp = (const float4*)(bc + t * 32);
    float4 b0 = Bp[0], b1 = Bp[1], b2 = Bp[2], b3 = Bp[3];
    float bb[DSTATE] = {b0.x, b0.y, b0.z, b0.w, b1.x, b1.y, b1.z, b1.w,
                        b2.x, b2.y, b2.z, b2.w, b3.x, b3.y, b3.z, b3.w};
#pragma unroll
    for (int n = 0; n < DSTATE; n++)
      h[n] = __expf(a[n] * dtv) * h[n] + dx * bb[n];
    Ssum += dtv;
  }
  float4* outp = (float4*)(Bc + ((size_t)c * NCH + ch) * DSTATE);
  outp[0] = make_float4(h[0], h[1], h[2], h[3]);
  outp[1] = make_float4(h[4], h[5], h[6], h[7]);
  outp[2] = make_float4(h[8], h[9], h[10], h[11]);
  outp[3] = make_float4(h[12], h[13], h[14], h[15]);
  S[c * NCH + ch] = Ssum;
}

__global__ __launch_bounds__(256) void scan_combine(
    const float* __restrict__ A_log, const float* __restrict__ S,
    float* BcHin) {
  int gid = blockIdx.x * 256 + threadIdx.x;
  int c = gid >> 4, n = gid & 15;
  int d = c & (DINNER - 1);
  float a = -__expf(A_log[d * DSTATE + n]);
  float h = 0.f;
  size_t base = (size_t)c * (NCH * DSTATE) + n;
  for (int ch = 0; ch < NCH; ch++) {
    float bcv = BcHin[base + (size_t)ch * DSTATE];
    float decay = __expf(a * S[c * NCH + ch]);
    BcHin[base + (size_t)ch * DSTATE] = h;
    h = decay * h + bcv;
  }
}

__global__ __launch_bounds__(256) void scan_chunk2(
    const float* __restrict__ dt, const ushort* __restrict__ xs,
    const float* __restrict__ bc, const ushort* __restrict__ gate,
    const float* __restrict__ A_log, const float* __restrict__ hin,
    ushort* __restrict__ y) {
  int blk = blockIdx.x;
  int b = blk >> 8;
  int rem = blk & 255;
  int ch = rem >> 3;
  int dblk = rem & 7;
  int d = dblk * 256 + threadIdx.x;
  int c = b * DINNER + d;
  float a[DSTATE];
#pragma unroll
  for (int i = 0; i < 4; i++) {
    float4 v = *(const float4*)(A_log + (size_t)d * DSTATE + 4 * i);
    a[4 * i + 0] = -__expf(v.x);
    a[4 * i + 1] = -__expf(v.y);
    a[4 * i + 2] = -__expf(v.z);
    a[4 * i + 3] = -__expf(v.w);
  }
  float h[DSTATE];
  const float4* hi = (const float4*)(hin + ((size_t)c * NCH + ch) * DSTATE);
#pragma unroll
  for (int i = 0; i < 4; i++) {
    float4 v = hi[i];
    h[4 * i + 0] = v.x; h[4 * i + 1] = v.y; h[4 * i + 2] = v.z; h[4 * i + 3] = v.w;
  }
  size_t t = (size_t)b * LSEQ + (size_t)ch * CL;
#pragma unroll 2
  for (int l = 0; l < CL; l++, t++) {
    float dtv = dt[t * DINNER + d];
    float dx = dtv * bf2f(xs[t * DINNER + d]);
    const float4* Bp = (const float4*)(bc + t * 32);
    const float4* Cp = (const float4*)(bc + t * 32 + 16);
    float4 b0 = Bp[0], b1 = Bp[1], b2 = Bp[2], b3 = Bp[3];
    float4 c0 = Cp[0], c1 = Cp[1], c2 = Cp[2], c3 = Cp[3];
    float bb[DSTATE] = {b0.x, b0.y, b0.z, b0.w, b1.x, b1.y, b1.z, b1.w,
                        b2.x, b2.y, b2.z, b2.w, b3.x, b3.y, b3.z, b3.w};
    float cc[DSTATE] = {c0.x, c0.y, c0.z, c0.w, c1.x, c1.y, c1.z, c1.w,
                        c2.x, c2.y, c2.z, c2.w, c3.x, c3.y, c3.z, c3.w};
    float ysum = 0.f;
#pragma unroll
    for (int n = 0; n < DSTATE; n++) {
      h[n] = __expf(a[n] * dtv) * h[n] + dx * bb[n];
      ysum = fmaf(h[n], cc[n], ysum);
    }
    y[t * DINNER + d] = f2bf(ysum * bf2f(gate[t * DINNER + d]));
  }
}

extern "C" void kernel_launch(void* const* d_in, const int* in_sizes, int n_in,
                              void* d_out, int out_size, void* d_ws, size_t ws_size,
                              hipStream_t stream) {
  const float* x      = (const float*)d_in[0];
  const float* rms_w  = (const float*)d_in[1];
  const float* W_in   = (const float*)d_in[2];
  const float* conv_w = (const float*)d_in[3];
  const float* conv_b = (const float*)d_in[4];
  const float* W_x    = (const float*)d_in[5];
  const float* W_dt   = (const float*)d_in[6];
  const float* A_log  = (const float*)d_in[7];
  const float* W_out  = (const float*)d_in[8];
  float* out = (float*)d_out;

  // workspace layout, byte offsets (total 92,536,832 B = same as R1 footprint)
  char* w = (char*)d_ws;
  ushort* xnb   = (ushort*)(w + 0);         //  4 MiB  [2048,1024] bf16 (dead after GEMM1)
  ushort* xsraw = (ushort*)(w + 4194304);   //  8 MiB  [2048,2048] bf16 (dead after conv)
  ushort* gate  = (ushort*)(w + 12582912);  //  8 MiB  silu(res) bf16
  ushort* xsb   = (ushort*)(w + 20971520);  //  8 MiB  conv+silu out bf16
  ushort* ssmb  = (ushort*)(w + 29360128);  //  8.125 MiB [2048,2080] bf16
  float*  dtb   = (float*)(w + 37879808);   // 16 MiB  softplus(dt) fp32
  ushort* yb    = (ushort*)(w + 54657024);  //  8 MiB  scan out bf16
  ushort* WinT  = (ushort*)(w + 63045632);  //  8 MiB  [4096,1024]
  ushort* WxT   = (ushort*)(w + 71434240);  //  8.125 MiB [2080,2048]
  ushort* WdtT  = (ushort*)(w + 79953920);  //  8 MiB  [2048,2048]
  ushort* WoutT = (ushort*)(w + 88342528);  //  4 MiB  [1024,2048]
  // overlays of dead regions:
  float* bc = (float*)(w + 0);        // [2048,32] fp32 B|C (over xnb, 256 KiB) - written by GEMM2
  float* S  = (float*)(w + 262144);   // [NC,NCH] fp32 (over xnb, 512 KiB)
  float* Bc = (float*)(w + 4194304);  // [NC,NCH,16] fp32 (over xsraw, 8 MiB exactly)

  transpose_w<<<dim3(64, 16), 256, 0, stream>>>(W_in, WinT, DMODEL, 4096);
  transpose_w<<<dim3(33, 32), 256, 0, stream>>>(W_x, WxT, DINNER, NSSM);
  transpose_w<<<dim3(32, 32), 256, 0, stream>>>(W_dt, WdtT, DINNER, DINNER);
  transpose_w<<<dim3(16, 32), 256, 0, stream>>>(W_out, WoutT, DINNER, DMODEL);

  rmsnorm_kernel<<<NTOK, 256, 0, stream>>>(x, rms_w, xnb);
  // xr = xn @ W_in : split -> xsraw (bf16), gate = silu(res) (bf16)
  gemm_mfma<<<dim3(32, 16), 256, 0, stream>>>(
      xnb, DMODEL, WinT, DMODEL, 4096, DMODEL, 1, xsraw, gate, nullptr);
  conv_silu_kernel<<<(NTOK * DINNER) / 256, 256, 0, stream>>>(xsraw, conv_w, conv_b, xsb);
  // ssm = xs @ W_x : bf16 full + fp32 B/C columns compact
  gemm_mfma<<<dim3(17, 16), 256, 0, stream>>>(
      xsb, DINNER, WxT, DINNER, NSSM, DINNER, 2, ssmb, bc, nullptr);
  // dt = softplus(ssm[:, :2048] @ W_dt) fp32
  gemm_mfma<<<dim3(16, 16), 256, 0, stream>>>(
      ssmb, NSSM, WdtT, DINNER, DINNER, DINNER, 3, dtb, nullptr, nullptr);
  // chunked scan
  scan_chunk1<<<B_SZ * NCH * 8, 256, 0, stream>>>(dtb, xsb, bc, A_log, Bc, S);
  scan_combine<<<(NC * DSTATE) / 256, 256, 0, stream>>>(A_log, S, Bc);
  scan_chunk2<<<B_SZ * NCH * 8, 256, 0, stream>>>(dtb, xsb, bc, gate, A_log, Bc, yb);
  // out = y @ W_out + x
  gemm_mfma<<<dim3(8, 16), 256, 0, stream>>>(
      yb, DINNER, WoutT, DINNER, DMODEL, DINNER, 0, out, nullptr, x);
}

// Round 8
// 332.839 us; speedup vs baseline: 1.3145x; 1.1563x over previous
//
#include <hip/hip_runtime.h>
#include <math.h>

#define B_SZ   2
#define LSEQ   1024
#define DMODEL 1024
#define DINNER 2048
#define DSTATE 16
#define NTOK   (B_SZ * LSEQ)          // 2048 tokens
#define NSSM   (DINNER + 2 * DSTATE)  // 2080
#define CL     16                     // scan chunk length
#define NCH    (LSEQ / CL)            // 64 chunks
#define NC     (B_SZ * DINNER)        // 4096 channels

typedef unsigned short ushort;
typedef __attribute__((ext_vector_type(8))) ushort ushort8;
typedef __attribute__((ext_vector_type(8))) __bf16 bf16x8;
typedef __attribute__((ext_vector_type(4))) float floatx4;

__device__ __forceinline__ float softplus_f(float x) {
  return (x > 20.f) ? x : __logf(1.f + __expf(x));
}
__device__ __forceinline__ float silu_f(float x) {
  return x / (1.f + __expf(-x));
}
__device__ __forceinline__ float bf2f(ushort u) {
  return __uint_as_float(((unsigned)u) << 16);
}
__device__ __forceinline__ ushort f2bf(float f) {  // round-to-nearest-even
  unsigned u = __float_as_uint(f);
  return (ushort)((u + 0x7FFFu + ((u >> 16) & 1u)) >> 16);
}

// ---------------- RMSNorm → bf16 ----------------
__global__ __launch_bounds__(256) void rmsnorm_kernel(
    const float* __restrict__ x, const float* __restrict__ w,
    ushort* __restrict__ xn) {
  int row = blockIdx.x;
  const float* xrow = x + (size_t)row * DMODEL;
  float v[4];
  float ss = 0.f;
#pragma unroll
  for (int i = 0; i < 4; i++) {
    v[i] = xrow[threadIdx.x + 256 * i];
    ss += v[i] * v[i];
  }
  __shared__ float wsum[4];
  int lane = threadIdx.x & 63, wid = threadIdx.x >> 6;
#pragma unroll
  for (int off = 1; off < 64; off <<= 1) ss += __shfl_xor(ss, off);
  if (lane == 0) wsum[wid] = ss;
  __syncthreads();
  float tot = wsum[0] + wsum[1] + wsum[2] + wsum[3];
  float scale = rsqrtf(tot / (float)DMODEL + 1e-5f);
#pragma unroll
  for (int i = 0; i < 4; i++) {
    int j = threadIdx.x + 256 * i;
    xn[(size_t)row * DMODEL + j] = f2bf(v[i] * scale * w[j]);
  }
}

// ---------------- fused: all 4 weights [K][N] fp32 → [N][K] bf16 ----------------
__global__ __launch_bounds__(256) void transpose_all(
    const float* __restrict__ Win, ushort* __restrict__ WinT,
    const float* __restrict__ Wx, ushort* __restrict__ WxT,
    const float* __restrict__ Wdt, ushort* __restrict__ WdtT,
    const float* __restrict__ Wout, ushort* __restrict__ WoutT) {
  int blk = blockIdx.x;
  const float* W; ushort* Wt; int K, N, nb, idx;
  if (blk < 1024)      { W = Win;  Wt = WinT;  K = DMODEL; N = 4096;  nb = 64; idx = blk; }
  else if (blk < 2080) { W = Wx;   Wt = WxT;   K = DINNER; N = NSSM;  nb = 33; idx = blk - 1024; }
  else if (blk < 3104) { W = Wdt;  Wt = WdtT;  K = DINNER; N = DINNER;nb = 32; idx = blk - 2080; }
  else                 { W = Wout; Wt = WoutT; K = DINNER; N = DMODEL;nb = 16; idx = blk - 3104; }
  int n0 = (idx % nb) * 64, k0 = (idx / nb) * 64;
  __shared__ float tile[64][65];
  int c = threadIdx.x & 63, rb = (threadIdx.x >> 6) << 4;
#pragma unroll
  for (int i = 0; i < 16; i++) {
    int k = k0 + rb + i;
    if (k < K && n0 + c < N) tile[rb + i][c] = W[(size_t)k * N + n0 + c];
  }
  __syncthreads();
#pragma unroll
  for (int i = 0; i < 16; i++) {
    int n = n0 + rb + i;
    if (n < N && k0 + c < K)
      Wt[(size_t)n * K + k0 + c] = f2bf(tile[c][rb + i]);
  }
}

// ---------------- bf16 MFMA GEMM: C[2048,N] = A[2048,K] @ Bt[N,K]^T ----------------
// 128x128 tile, BK=64 (two 32-k panels per barrier pair), 4 waves, 64x64/wave.
// Register-prefetched staging + LDS double-buffer + ONE barrier per K-iter.
// K here = per-launch K length; splitk: blockIdx.z selects K-slice and partial slab.
// mode 0: C0=fp32 raw store (ldc=N; + blockIdx.z*M*N for split-K partials)
// mode 1: n<2048 -> C0=bf16 xsraw; n>=2048 -> C1=bf16 silu() gate   (N=4096)
// mode 2: C0=bf16 ssm (ld NSSM); n>=2048 -> C1=fp32 bc[m][n-2048] (ld 32)
// mode 3: C0=fp32 softplus()  (ld DINNER)
__global__ __launch_bounds__(256, 2) void gemm_mfma(
    const ushort* __restrict__ A, int lda,
    const ushort* __restrict__ Bt, int ldb,
    int N, int K, int mode,
    void* __restrict__ C0, void* __restrict__ C1,
    const float* __restrict__ addend) {
  // [dbuf][panel][128 rows][32 ushorts]
  __shared__ ushort As[2 * 2 * 128 * 32];  // 32 KB
  __shared__ ushort Bs[2 * 2 * 128 * 32];  // 32 KB
  const int bm = blockIdx.y * 128, bn = blockIdx.x * 128;
  const int tid = threadIdx.x;
  const int wave = tid >> 6, lane = tid & 63;
  const int wm = (wave & 1) << 6, wn = (wave >> 1) << 6;
  const int lrow = lane & 15, quad = lane >> 4;
  const size_t koff = (size_t)blockIdx.z * K;  // split-K slice start

  // staging: thread t owns rows (t>>2) and (t>>2)+64, logical k-block t&3 (per panel).
  const int sr = tid >> 2;                    // 0..63
  const int q  = tid & 3;                     // logical 16B k-block within panel
  const int swr = (sr ^ (sr >> 2)) & 3;
  const int pq = (q ^ swr) << 3;              // physical ushort offset in row
  const int br0 = min(bn + sr, N - 1);        // clamp tail (global side only)
  const int br1 = min(bn + sr + 64, N - 1);
  const ushort* ga0 = A + (size_t)(bm + sr) * lda + koff + (q << 3);
  const ushort* ga1 = A + (size_t)(bm + sr + 64) * lda + koff + (q << 3);
  const ushort* gb0 = Bt + (size_t)br0 * ldb + koff + (q << 3);
  const ushort* gb1 = Bt + (size_t)br1 * ldb + koff + (q << 3);

  floatx4 acc[4][4];
#pragma unroll
  for (int i = 0; i < 4; i++)
#pragma unroll
    for (int j = 0; j < 4; j++) acc[i][j] = (floatx4){0.f, 0.f, 0.f, 0.f};

  // frag-read swizzle (row-local, matches staging)
  const int swf = ((lrow ^ (lrow >> 2)) & 3);
  const int fq = ((quad ^ swf) << 3);

  const int nk = K >> 6;  // BK=64
  ushort8 ra[2][2], rb[2][2];  // [panel][row-half]
#pragma unroll
  for (int p = 0; p < 2; p++) {
    ra[p][0] = *(const ushort8*)(ga0 + p * 32);
    ra[p][1] = *(const ushort8*)(ga1 + p * 32);
    rb[p][0] = *(const ushort8*)(gb0 + p * 32);
    rb[p][1] = *(const ushort8*)(gb1 + p * 32);
  }
  for (int kt = 0; kt < nk; kt++) {
    const int bo = (kt & 1) << 13;  // 8192 ushorts per dbuf slot
#pragma unroll
    for (int p = 0; p < 2; p++) {
      const int po = bo + (p << 12);
      *(ushort8*)&As[po + sr * 32 + pq] = ra[p][0];
      *(ushort8*)&As[po + (sr + 64) * 32 + pq] = ra[p][1];
      *(ushort8*)&Bs[po + sr * 32 + pq] = rb[p][0];
      *(ushort8*)&Bs[po + (sr + 64) * 32 + pq] = rb[p][1];
    }
    __syncthreads();
    if (kt + 1 < nk) {  // VGPR prefetch; lands any time before next iter's write
      const int ko = (kt + 1) << 6;
#pragma unroll
      for (int p = 0; p < 2; p++) {
        ra[p][0] = *(const ushort8*)(ga0 + ko + p * 32);
        ra[p][1] = *(const ushort8*)(ga1 + ko + p * 32);
        rb[p][0] = *(const ushort8*)(gb0 + ko + p * 32);
        rb[p][1] = *(const ushort8*)(gb1 + ko + p * 32);
      }
    }
#pragma unroll
    for (int p = 0; p < 2; p++) {
      const int po = bo + (p << 12);
      bf16x8 af[4], bfr[4];
#pragma unroll
      for (int i = 0; i < 4; i++)
        af[i] = __builtin_bit_cast(bf16x8,
            *(const ushort8*)&As[po + (wm + i * 16 + lrow) * 32 + fq]);
#pragma unroll
      for (int j = 0; j < 4; j++)
        bfr[j] = __builtin_bit_cast(bf16x8,
            *(const ushort8*)&Bs[po + (wn + j * 16 + lrow) * 32 + fq]);
#pragma unroll
      for (int i = 0; i < 4; i++)
#pragma unroll
        for (int j = 0; j < 4; j++)
          acc[i][j] = __builtin_amdgcn_mfma_f32_16x16x32_bf16(
              af[i], bfr[j], acc[i][j], 0, 0, 0);
    }
  }
  // epilogue: D row = quad*4+r, col = lane&15  [m89-verified]
  const int m0 = bm + wm, n0 = bn + wn, rq = quad << 2;
  float* P = (float*)C0 + (size_t)blockIdx.z * NTOK * N;  // mode-0 partial slab
#pragma unroll
  for (int i = 0; i < 4; i++) {
#pragma unroll
    for (int j = 0; j < 4; j++) {
#pragma unroll
      for (int r = 0; r < 4; r++) {
        int m = m0 + i * 16 + rq + r;
        int n = n0 + j * 16 + lrow;
        if (n >= N) continue;
        float v = acc[i][j][r];
        if (mode == 0) {
          P[(size_t)m * N + n] = v;
        } else if (mode == 1) {
          if (n < DINNER)
            ((ushort*)C0)[(size_t)m * DINNER + n] = f2bf(v);
          else
            ((ushort*)C1)[(size_t)m * DINNER + n - DINNER] = f2bf(silu_f(v));
        } else if (mode == 2) {
          ((ushort*)C0)[(size_t)m * NSSM + n] = f2bf(v);
          if (n >= DINNER)
            ((float*)C1)[(size_t)m * 32 + n - DINNER] = v;
        } else {
          ((float*)C0)[(size_t)m * DINNER + n] = softplus_f(v);
        }
      }
    }
  }
}

// ---------------- split-K reduce + residual for W_out ----------------
__global__ __launch_bounds__(256) void reduce_wout(
    const float* __restrict__ P, const float* __restrict__ x,
    float* __restrict__ out) {
  int gid = blockIdx.x * 256 + threadIdx.x;  // float4 index
  const float4 a = ((const float4*)P)[gid];
  const float4 b = ((const float4*)P)[gid + (NTOK * DMODEL / 4)];
  const float4 r = ((const float4*)x)[gid];
  ((float4*)out)[gid] = make_float4(a.x + b.x + r.x, a.y + b.y + r.y,
                                    a.z + b.z + r.z, a.w + b.w + r.w);
}

// ---------------- causal depthwise conv(4) + bias + silu (bf16 in/out) ----------------
__global__ __launch_bounds__(256) void conv_silu_kernel(
    const ushort* __restrict__ xsraw, const float* __restrict__ cw,
    const float* __restrict__ cb, ushort* __restrict__ xs) {
  int gid = blockIdx.x * 256 + threadIdx.x;
  int c = gid & (DINNER - 1);
  int t = gid >> 11;
  int l = t & (LSEQ - 1);
  float w0 = cw[c * 4 + 0], w1 = cw[c * 4 + 1], w2 = cw[c * 4 + 2], w3 = cw[c * 4 + 3];
  const ushort* col = xsraw + (size_t)t * DINNER + c;
  float acc = cb[c] + w3 * bf2f(col[0]);
  if (l >= 1) acc += w2 * bf2f(col[-DINNER]);
  if (l >= 2) acc += w1 * bf2f(col[-2 * DINNER]);
  if (l >= 3) acc += w0 * bf2f(col[-3 * DINNER]);
  xs[gid] = f2bf(silu_f(acc));
}

// ---------------- chunked selective scan (h[16]/thread, fp32 state) ----------------
__global__ __launch_bounds__(256) void scan_chunk1(
    const float* __restrict__ dt, const ushort* __restrict__ xs,
    const float* __restrict__ bc, const float* __restrict__ A_log,
    float* __restrict__ Bc, float* __restrict__ S) {
  int blk = blockIdx.x;                 // [0, B_SZ*NCH*8)
  int b = blk >> 9;                     // / (NCH*8)
  int rem = blk & 511;
  int ch = rem >> 3;
  int dblk = rem & 7;
  int d = dblk * 256 + threadIdx.x;
  int c = b * DINNER + d;
  float a[DSTATE];
#pragma unroll
  for (int i = 0; i < 4; i++) {
    float4 v = *(const float4*)(A_log + (size_t)d * DSTATE + 4 * i);
    a[4 * i + 0] = -__expf(v.x);
    a[4 * i + 1] = -__expf(v.y);
    a[4 * i + 2] = -__expf(v.z);
    a[4 * i + 3] = -__expf(v.w);
  }
  float h[DSTATE] = {};
  float Ssum = 0.f;
  size_t t = (size_t)b * LSEQ + (size_t)ch * CL;
#pragma unroll 2
  for (int l = 0; l < CL; l++, t++) {
    float dtv = dt[t * DINNER + d];
    float dx = dtv * bf2f(xs[t * DINNER + d]);
    const float4* Bp = (const float4*)(bc + t * 32);
    float4 b0 = Bp[0], b1 = Bp[1], b2 = Bp[2], b3 = Bp[3];
    float bb[DSTATE] = {b0.x, b0.y, b0.z, b0.w, b1.x, b1.y, b1.z, b1.w,
                        b2.x, b2.y, b2.z, b2.w, b3.x, b3.y, b3.z, b3.w};
#pragma unroll
    for (int n = 0; n < DSTATE; n++)
      h[n] = __expf(a[n] * dtv) * h[n] + dx * bb[n];
    Ssum += dtv;
  }
  float4* outp = (float4*)(Bc + ((size_t)c * NCH + ch) * DSTATE);
  outp[0] = make_float4(h[0], h[1], h[2], h[3]);
  outp[1] = make_float4(h[4], h[5], h[6], h[7]);
  outp[2] = make_float4(h[8], h[9], h[10], h[11]);
  outp[3] = make_float4(h[12], h[13], h[14], h[15]);
  S[c * NCH + ch] = Ssum;
}

__global__ __launch_bounds__(256) void scan_combine(
    const float* __restrict__ A_log, const float* __restrict__ S,
    float* BcHin) {
  int gid = blockIdx.x * 256 + threadIdx.x;  // [0, NC*DSTATE)
  int c = gid >> 4, n = gid & 15;
  int d = c & (DINNER - 1);
  float a = -__expf(A_log[d * DSTATE + n]);
  float h = 0.f;
  size_t base = (size_t)c * (NCH * DSTATE) + n;
  for (int ch = 0; ch < NCH; ch++) {
    float bcv = BcHin[base + (size_t)ch * DSTATE];
    float decay = __expf(a * S[c * NCH + ch]);
    BcHin[base + (size_t)ch * DSTATE] = h;
    h = decay * h + bcv;
  }
}

__global__ __launch_bounds__(256) void scan_chunk2(
    const float* __restrict__ dt, const ushort* __restrict__ xs,
    const float* __restrict__ bc, const ushort* __restrict__ gate,
    const float* __restrict__ A_log, const float* __restrict__ hin,
    ushort* __restrict__ y) {
  int blk = blockIdx.x;
  int b = blk >> 9;
  int rem = blk & 511;
  int ch = rem >> 3;
  int dblk = rem & 7;
  int d = dblk * 256 + threadIdx.x;
  int c = b * DINNER + d;
  float a[DSTATE];
#pragma unroll
  for (int i = 0; i < 4; i++) {
    float4 v = *(const float4*)(A_log + (size_t)d * DSTATE + 4 * i);
    a[4 * i + 0] = -__expf(v.x);
    a[4 * i + 1] = -__expf(v.y);
    a[4 * i + 2] = -__expf(v.z);
    a[4 * i + 3] = -__expf(v.w);
  }
  float h[DSTATE];
  const float4* hi = (const float4*)(hin + ((size_t)c * NCH + ch) * DSTATE);
#pragma unroll
  for (int i = 0; i < 4; i++) {
    float4 v = hi[i];
    h[4 * i + 0] = v.x; h[4 * i + 1] = v.y; h[4 * i + 2] = v.z; h[4 * i + 3] = v.w;
  }
  size_t t = (size_t)b * LSEQ + (size_t)ch * CL;
#pragma unroll 2
  for (int l = 0; l < CL; l++, t++) {
    float dtv = dt[t * DINNER + d];
    float dx = dtv * bf2f(xs[t * DINNER + d]);
    const float4* Bp = (const float4*)(bc + t * 32);
    const float4* Cp = (const float4*)(bc + t * 32 + 16);
    float4 b0 = Bp[0], b1 = Bp[1], b2 = Bp[2], b3 = Bp[3];
    float4 c0 = Cp[0], c1 = Cp[1], c2 = Cp[2], c3 = Cp[3];
    float bb[DSTATE] = {b0.x, b0.y, b0.z, b0.w, b1.x, b1.y, b1.z, b1.w,
                        b2.x, b2.y, b2.z, b2.w, b3.x, b3.y, b3.z, b3.w};
    float cc[DSTATE] = {c0.x, c0.y, c0.z, c0.w, c1.x, c1.y, c1.z, c1.w,
                        c2.x, c2.y, c2.z, c2.w, c3.x, c3.y, c3.z, c3.w};
    float ysum = 0.f;
#pragma unroll
    for (int n = 0; n < DSTATE; n++) {
      h[n] = __expf(a[n] * dtv) * h[n] + dx * bb[n];
      ysum = fmaf(h[n], cc[n], ysum);
    }
    y[t * DINNER + d] = f2bf(ysum * bf2f(gate[t * DINNER + d]));
  }
}

extern "C" void kernel_launch(void* const* d_in, const int* in_sizes, int n_in,
                              void* d_out, int out_size, void* d_ws, size_t ws_size,
                              hipStream_t stream) {
  const float* x      = (const float*)d_in[0];
  const float* rms_w  = (const float*)d_in[1];
  const float* W_in   = (const float*)d_in[2];
  const float* conv_w = (const float*)d_in[3];
  const float* conv_b = (const float*)d_in[4];
  const float* W_x    = (const float*)d_in[5];
  const float* W_dt   = (const float*)d_in[6];
  const float* A_log  = (const float*)d_in[7];
  const float* W_out  = (const float*)d_in[8];
  float* out = (float*)d_out;

  // workspace layout, byte offsets (total 92,536,832 B)
  char* w = (char*)d_ws;
  ushort* xnb   = (ushort*)(w + 0);         //  4 MiB  bf16 xn (dead after GEMM1)
  ushort* xsraw = (ushort*)(w + 4194304);   //  8 MiB  bf16 (dead after conv)
  ushort* gate  = (ushort*)(w + 12582912);  //  8 MiB  silu(res) bf16 (dead after chunk2)
  ushort* xsb   = (ushort*)(w + 20971520);  //  8 MiB  conv+silu out bf16
  ushort* ssmb  = (ushort*)(w + 29360128);  //  8.125 MiB [2048,2080] bf16
  float*  dtb   = (float*)(w + 37879808);   // 16 MiB  softplus(dt) fp32
  ushort* yb    = (ushort*)(w + 54657024);  //  8 MiB  scan out bf16
  ushort* WinT  = (ushort*)(w + 63045632);  //  8 MiB  (dead after GEMM1)
  ushort* WxT   = (ushort*)(w + 71434240);  //  8.125 MiB (dead after GEMM2)
  ushort* WdtT  = (ushort*)(w + 79953920);  //  8 MiB  (dead after GEMM3)
  ushort* WoutT = (ushort*)(w + 88342528);  //  4 MiB
  // overlays of dead regions:
  float* bc = (float*)(w + 0);          // [2048,32] fp32 B|C (over xnb) — GEMM2 writes
  float* Bc = (float*)(w + 63045632);   // [NC,NCH,16] fp32 = 16 MiB over WinT+WxT (chunk1 after GEMM2)
  float* S  = (float*)(w + 79953920);   // [NC,NCH] fp32 = 1 MiB over WdtT (after GEMM3)
  float* P  = (float*)(w + 4194304);    // [2][2048,1024] fp32 = 16 MiB over xsraw+gate (after chunk2)

  transpose_all<<<3616, 256, 0, stream>>>(W_in, WinT, W_x, WxT, W_dt, WdtT, W_out, WoutT);

  rmsnorm_kernel<<<NTOK, 256, 0, stream>>>(x, rms_w, xnb);
  // xr = xn @ W_in : split -> xsraw (bf16), gate = silu(res) (bf16)
  gemm_mfma<<<dim3(32, 16), 256, 0, stream>>>(
      xnb, DMODEL, WinT, DMODEL, 4096, DMODEL, 1, xsraw, gate, nullptr);
  conv_silu_kernel<<<(NTOK * DINNER) / 256, 256, 0, stream>>>(xsraw, conv_w, conv_b, xsb);
  // ssm = xs @ W_x : bf16 full + fp32 B/C columns compact
  gemm_mfma<<<dim3(17, 16), 256, 0, stream>>>(
      xsb, DINNER, WxT, DINNER, NSSM, DINNER, 2, ssmb, bc, nullptr);
  // dt = softplus(ssm[:, :2048] @ W_dt) fp32
  gemm_mfma<<<dim3(16, 16), 256, 0, stream>>>(
      ssmb, NSSM, WdtT, DINNER, DINNER, DINNER, 3, dtb, nullptr, nullptr);
  // chunked scan
  scan_chunk1<<<B_SZ * NCH * 8, 256, 0, stream>>>(dtb, xsb, bc, A_log, Bc, S);
  scan_combine<<<(NC * DSTATE) / 256, 256, 0, stream>>>(A_log, S, Bc);
  scan_chunk2<<<B_SZ * NCH * 8, 256, 0, stream>>>(dtb, xsb, bc, gate, A_log, Bc, yb);
  // out = y @ W_out + x : split-K x2 (z = K-slice) then reduce+residual
  gemm_mfma<<<dim3(8, 16, 2), 256, 0, stream>>>(
      yb, DINNER, WoutT, DINNER, DMODEL, DINNER / 2, 0, P, nullptr, nullptr);
  reduce_wout<<<(NTOK * DMODEL / 4) / 256, 256, 0, stream>>>(P, x, out);
}

// Round 9
// 327.165 us; speedup vs baseline: 1.3373x; 1.0173x over previous
//
#include <hip/hip_runtime.h>
#include <math.h>

#define B_SZ   2
#define LSEQ   1024
#define DMODEL 1024
#define DINNER 2048
#define DSTATE 16
#define NTOK   (B_SZ * LSEQ)          // 2048 tokens
#define NSSM   (DINNER + 2 * DSTATE)  // 2080
#define CL     16                     // scan chunk length
#define NCH    (LSEQ / CL)            // 64 chunks
#define NC     (B_SZ * DINNER)        // 4096 channels

typedef unsigned short ushort;
typedef __attribute__((ext_vector_type(8))) ushort ushort8;
typedef __attribute__((ext_vector_type(8))) __bf16 bf16x8;
typedef __attribute__((ext_vector_type(4))) float floatx4;

__device__ __forceinline__ float softplus_f(float x) {
  return (x > 20.f) ? x : __logf(1.f + __expf(x));
}
__device__ __forceinline__ float silu_f(float x) {
  return x / (1.f + __expf(-x));
}
__device__ __forceinline__ float bf2f(ushort u) {
  return __uint_as_float(((unsigned)u) << 16);
}
__device__ __forceinline__ ushort f2bf(float f) {  // round-to-nearest-even
  unsigned u = __float_as_uint(f);
  return (ushort)((u + 0x7FFFu + ((u >> 16) & 1u)) >> 16);
}

// ---------------- RMSNorm → bf16 ----------------
__global__ __launch_bounds__(256) void rmsnorm_kernel(
    const float* __restrict__ x, const float* __restrict__ w,
    ushort* __restrict__ xn) {
  int row = blockIdx.x;
  const float* xrow = x + (size_t)row * DMODEL;
  float v[4];
  float ss = 0.f;
#pragma unroll
  for (int i = 0; i < 4; i++) {
    v[i] = xrow[threadIdx.x + 256 * i];
    ss += v[i] * v[i];
  }
  __shared__ float wsum[4];
  int lane = threadIdx.x & 63, wid = threadIdx.x >> 6;
#pragma unroll
  for (int off = 1; off < 64; off <<= 1) ss += __shfl_xor(ss, off);
  if (lane == 0) wsum[wid] = ss;
  __syncthreads();
  float tot = wsum[0] + wsum[1] + wsum[2] + wsum[3];
  float scale = rsqrtf(tot / (float)DMODEL + 1e-5f);
#pragma unroll
  for (int i = 0; i < 4; i++) {
    int j = threadIdx.x + 256 * i;
    xn[(size_t)row * DMODEL + j] = f2bf(v[i] * scale * w[j]);
  }
}

// ---------------- fused: all 4 weights [K][N] fp32 → [N][K] bf16 ----------------
__global__ __launch_bounds__(256) void transpose_all(
    const float* __restrict__ Win, ushort* __restrict__ WinT,
    const float* __restrict__ Wx, ushort* __restrict__ WxT,
    const float* __restrict__ Wdt, ushort* __restrict__ WdtT,
    const float* __restrict__ Wout, ushort* __restrict__ WoutT) {
  int blk = blockIdx.x;
  const float* W; ushort* Wt; int K, N, nb, idx;
  if (blk < 1024)      { W = Win;  Wt = WinT;  K = DMODEL; N = 4096;  nb = 64; idx = blk; }
  else if (blk < 2080) { W = Wx;   Wt = WxT;   K = DINNER; N = NSSM;  nb = 33; idx = blk - 1024; }
  else if (blk < 3104) { W = Wdt;  Wt = WdtT;  K = DINNER; N = DINNER;nb = 32; idx = blk - 2080; }
  else                 { W = Wout; Wt = WoutT; K = DINNER; N = DMODEL;nb = 16; idx = blk - 3104; }
  int n0 = (idx % nb) * 64, k0 = (idx / nb) * 64;
  __shared__ float tile[64][65];
  int c = threadIdx.x & 63, rb = (threadIdx.x >> 6) << 4;
#pragma unroll
  for (int i = 0; i < 16; i++) {
    int k = k0 + rb + i;
    if (k < K && n0 + c < N) tile[rb + i][c] = W[(size_t)k * N + n0 + c];
  }
  __syncthreads();
#pragma unroll
  for (int i = 0; i < 16; i++) {
    int n = n0 + rb + i;
    if (n < N && k0 + c < K)
      Wt[(size_t)n * K + k0 + c] = f2bf(tile[c][rb + i]);
  }
}

// ---------------- bf16 MFMA GEMM: C[2048,N] = A[2048,K] @ Bt[N,K]^T ----------------
// 128(M)x64(N) tile, BK=64 (two 32-k panels), 4 waves, each wave 64x32 C-tile.
// Register-prefetched staging + LDS double-buffer + ONE barrier per K-iter.
// Smaller N-tile doubles the grid -> 2-3 blocks/CU resident (latency hiding).
// K here = per-launch K length; splitk: blockIdx.z selects K-slice and partial slab.
// mode 0: C0=fp32 raw store (ldc=N; + blockIdx.z*M*N for split-K partials)
// mode 1: n<2048 -> C0=bf16 xsraw; n>=2048 -> C1=bf16 silu() gate   (N=4096)
// mode 2: C0=bf16 ssm (ld NSSM); n>=2048 -> C1=fp32 bc[m][n-2048] (ld 32)
// mode 3: C0=fp32 softplus()  (ld DINNER)
__global__ __launch_bounds__(256, 3) void gemm_mfma(
    const ushort* __restrict__ A, int lda,
    const ushort* __restrict__ Bt, int ldb,
    int N, int K, int mode,
    void* __restrict__ C0, void* __restrict__ C1,
    const float* __restrict__ addend) {
  // [dbuf][panel][rows][32 ushorts]
  __shared__ ushort As[2 * 2 * 128 * 32];  // 32 KB
  __shared__ ushort Bs[2 * 2 * 64 * 32];   // 16 KB
  const int bm = blockIdx.y * 128, bn = blockIdx.x * 64;
  const int tid = threadIdx.x;
  const int wave = tid >> 6, lane = tid & 63;
  const int wm = (wave & 1) << 6, wn = (wave >> 1) << 5;  // 64x32 per wave
  const int lrow = lane & 15, quad = lane >> 4;
  const size_t koff = (size_t)blockIdx.z * K;  // split-K slice start

  // staging: thread t owns A-rows (t>>2), (t>>2)+64 and B-row (t>>2); k-block t&3.
  const int sr = tid >> 2;                    // 0..63
  const int q  = tid & 3;                     // logical 16B k-block within panel
  const int swr = (sr ^ (sr >> 2)) & 3;
  const int pq = (q ^ swr) << 3;              // physical ushort offset in row
  const int brow = min(bn + sr, N - 1);       // clamp tail (global side only)
  const ushort* ga0 = A + (size_t)(bm + sr) * lda + koff + (q << 3);
  const ushort* ga1 = A + (size_t)(bm + sr + 64) * lda + koff + (q << 3);
  const ushort* gb0 = Bt + (size_t)brow * ldb + koff + (q << 3);

  floatx4 acc[4][2];
#pragma unroll
  for (int i = 0; i < 4; i++)
#pragma unroll
    for (int j = 0; j < 2; j++) acc[i][j] = (floatx4){0.f, 0.f, 0.f, 0.f};

  // frag-read swizzle (row-local, matches staging)
  const int swf = ((lrow ^ (lrow >> 2)) & 3);
  const int fq = ((quad ^ swf) << 3);

  const int nk = K >> 6;  // BK=64
  ushort8 ra[2][2], rbv[2];  // [panel][A row-half], [panel] for B
#pragma unroll
  for (int p = 0; p < 2; p++) {
    ra[p][0] = *(const ushort8*)(ga0 + p * 32);
    ra[p][1] = *(const ushort8*)(ga1 + p * 32);
    rbv[p]   = *(const ushort8*)(gb0 + p * 32);
  }
  for (int kt = 0; kt < nk; kt++) {
    const int boA = (kt & 1) << 13;  // 8192 ushorts per A dbuf slot
    const int boB = (kt & 1) << 12;  // 4096 ushorts per B dbuf slot
#pragma unroll
    for (int p = 0; p < 2; p++) {
      *(ushort8*)&As[boA + (p << 12) + sr * 32 + pq] = ra[p][0];
      *(ushort8*)&As[boA + (p << 12) + (sr + 64) * 32 + pq] = ra[p][1];
      *(ushort8*)&Bs[boB + (p << 11) + sr * 32 + pq] = rbv[p];
    }
    __syncthreads();
    if (kt + 1 < nk) {  // VGPR prefetch; lands any time before next iter's write
      const int ko = (kt + 1) << 6;
#pragma unroll
      for (int p = 0; p < 2; p++) {
        ra[p][0] = *(const ushort8*)(ga0 + ko + p * 32);
        ra[p][1] = *(const ushort8*)(ga1 + ko + p * 32);
        rbv[p]   = *(const ushort8*)(gb0 + ko + p * 32);
      }
    }
#pragma unroll
    for (int p = 0; p < 2; p++) {
      bf16x8 af[4], bfr[2];
#pragma unroll
      for (int i = 0; i < 4; i++)
        af[i] = __builtin_bit_cast(bf16x8,
            *(const ushort8*)&As[boA + (p << 12) + (wm + i * 16 + lrow) * 32 + fq]);
#pragma unroll
      for (int j = 0; j < 2; j++)
        bfr[j] = __builtin_bit_cast(bf16x8,
            *(const ushort8*)&Bs[boB + (p << 11) + (wn + j * 16 + lrow) * 32 + fq]);
#pragma unroll
      for (int i = 0; i < 4; i++)
#pragma unroll
        for (int j = 0; j < 2; j++)
          acc[i][j] = __builtin_amdgcn_mfma_f32_16x16x32_bf16(
              af[i], bfr[j], acc[i][j], 0, 0, 0);
    }
  }
  // epilogue: D row = quad*4+r, col = lane&15  [m89-verified]
  const int m0 = bm + wm, n0 = bn + wn, rq = quad << 2;
  float* P = (float*)C0 + (size_t)blockIdx.z * NTOK * N;  // mode-0 partial slab
#pragma unroll
  for (int i = 0; i < 4; i++) {
#pragma unroll
    for (int j = 0; j < 2; j++) {
#pragma unroll
      for (int r = 0; r < 4; r++) {
        int m = m0 + i * 16 + rq + r;
        int n = n0 + j * 16 + lrow;
        if (n >= N) continue;
        float v = acc[i][j][r];
        if (mode == 0) {
          P[(size_t)m * N + n] = v;
        } else if (mode == 1) {
          if (n < DINNER)
            ((ushort*)C0)[(size_t)m * DINNER + n] = f2bf(v);
          else
            ((ushort*)C1)[(size_t)m * DINNER + n - DINNER] = f2bf(silu_f(v));
        } else if (mode == 2) {
          ((ushort*)C0)[(size_t)m * NSSM + n] = f2bf(v);
          if (n >= DINNER)
            ((float*)C1)[(size_t)m * 32 + n - DINNER] = v;
        } else {
          ((float*)C0)[(size_t)m * DINNER + n] = softplus_f(v);
        }
      }
    }
  }
}

// ---------------- split-K reduce + residual for W_out ----------------
__global__ __launch_bounds__(256) void reduce_wout(
    const float* __restrict__ P, const float* __restrict__ x,
    float* __restrict__ out) {
  int gid = blockIdx.x * 256 + threadIdx.x;  // float4 index
  const float4 a = ((const float4*)P)[gid];
  const float4 b = ((const float4*)P)[gid + (NTOK * DMODEL / 4)];
  const float4 r = ((const float4*)x)[gid];
  ((float4*)out)[gid] = make_float4(a.x + b.x + r.x, a.y + b.y + r.y,
                                    a.z + b.z + r.z, a.w + b.w + r.w);
}

// ---------------- causal depthwise conv(4) + bias + silu (bf16 in/out) ----------------
__global__ __launch_bounds__(256) void conv_silu_kernel(
    const ushort* __restrict__ xsraw, const float* __restrict__ cw,
    const float* __restrict__ cb, ushort* __restrict__ xs) {
  int gid = blockIdx.x * 256 + threadIdx.x;
  int c = gid & (DINNER - 1);
  int t = gid >> 11;
  int l = t & (LSEQ - 1);
  float w0 = cw[c * 4 + 0], w1 = cw[c * 4 + 1], w2 = cw[c * 4 + 2], w3 = cw[c * 4 + 3];
  const ushort* col = xsraw + (size_t)t * DINNER + c;
  float acc = cb[c] + w3 * bf2f(col[0]);
  if (l >= 1) acc += w2 * bf2f(col[-DINNER]);
  if (l >= 2) acc += w1 * bf2f(col[-2 * DINNER]);
  if (l >= 3) acc += w0 * bf2f(col[-3 * DINNER]);
  xs[gid] = f2bf(silu_f(acc));
}

// ---------------- chunked selective scan (h[16]/thread, fp32 state) ----------------
__global__ __launch_bounds__(256) void scan_chunk1(
    const float* __restrict__ dt, const ushort* __restrict__ xs,
    const float* __restrict__ bc, const float* __restrict__ A_log,
    float* __restrict__ Bc, float* __restrict__ S) {
  int blk = blockIdx.x;                 // [0, B_SZ*NCH*8)
  int b = blk >> 9;                     // / (NCH*8)
  int rem = blk & 511;
  int ch = rem >> 3;
  int dblk = rem & 7;
  int d = dblk * 256 + threadIdx.x;
  int c = b * DINNER + d;
  float a[DSTATE];
#pragma unroll
  for (int i = 0; i < 4; i++) {
    float4 v = *(const float4*)(A_log + (size_t)d * DSTATE + 4 * i);
    a[4 * i + 0] = -__expf(v.x);
    a[4 * i + 1] = -__expf(v.y);
    a[4 * i + 2] = -__expf(v.z);
    a[4 * i + 3] = -__expf(v.w);
  }
  float h[DSTATE] = {};
  float Ssum = 0.f;
  size_t t = (size_t)b * LSEQ + (size_t)ch * CL;
#pragma unroll 2
  for (int l = 0; l < CL; l++, t++) {
    float dtv = dt[t * DINNER + d];
    float dx = dtv * bf2f(xs[t * DINNER + d]);
    const float4* Bp = (const float4*)(bc + t * 32);
    float4 b0 = Bp[0], b1 = Bp[1], b2 = Bp[2], b3 = Bp[3];
    float bb[DSTATE] = {b0.x, b0.y, b0.z, b0.w, b1.x, b1.y, b1.z, b1.w,
                        b2.x, b2.y, b2.z, b2.w, b3.x, b3.y, b3.z, b3.w};
#pragma unroll
    for (int n = 0; n < DSTATE; n++)
      h[n] = __expf(a[n] * dtv) * h[n] + dx * bb[n];
    Ssum += dtv;
  }
  float4* outp = (float4*)(Bc + ((size_t)c * NCH + ch) * DSTATE);
  outp[0] = make_float4(h[0], h[1], h[2], h[3]);
  outp[1] = make_float4(h[4], h[5], h[6], h[7]);
  outp[2] = make_float4(h[8], h[9], h[10], h[11]);
  outp[3] = make_float4(h[12], h[13], h[14], h[15]);
  S[c * NCH + ch] = Ssum;
}

__global__ __launch_bounds__(256) void scan_combine(
    const float* __restrict__ A_log, const float* __restrict__ S,
    float* BcHin) {
  int gid = blockIdx.x * 256 + threadIdx.x;  // [0, NC*DSTATE)
  int c = gid >> 4, n = gid & 15;
  int d = c & (DINNER - 1);
  float a = -__expf(A_log[d * DSTATE + n]);
  float h = 0.f;
  size_t base = (size_t)c * (NCH * DSTATE) + n;
  for (int ch = 0; ch < NCH; ch++) {
    float bcv = BcHin[base + (size_t)ch * DSTATE];
    float decay = __expf(a * S[c * NCH + ch]);
    BcHin[base + (size_t)ch * DSTATE] = h;
    h = decay * h + bcv;
  }
}

__global__ __launch_bounds__(256) void scan_chunk2(
    const float* __restrict__ dt, const ushort* __restrict__ xs,
    const float* __restrict__ bc, const ushort* __restrict__ gate,
    const float* __restrict__ A_log, const float* __restrict__ hin,
    ushort* __restrict__ y) {
  int blk = blockIdx.x;
  int b = blk >> 9;
  int rem = blk & 511;
  int ch = rem >> 3;
  int dblk = rem & 7;
  int d = dblk * 256 + threadIdx.x;
  int c = b * DINNER + d;
  float a[DSTATE];
#pragma unroll
  for (int i = 0; i < 4; i++) {
    float4 v = *(const float4*)(A_log + (size_t)d * DSTATE + 4 * i);
    a[4 * i + 0] = -__expf(v.x);
    a[4 * i + 1] = -__expf(v.y);
    a[4 * i + 2] = -__expf(v.z);
    a[4 * i + 3] = -__expf(v.w);
  }
  float h[DSTATE];
  const float4* hi = (const float4*)(hin + ((size_t)c * NCH + ch) * DSTATE);
#pragma unroll
  for (int i = 0; i < 4; i++) {
    float4 v = hi[i];
    h[4 * i + 0] = v.x; h[4 * i + 1] = v.y; h[4 * i + 2] = v.z; h[4 * i + 3] = v.w;
  }
  size_t t = (size_t)b * LSEQ + (size_t)ch * CL;
#pragma unroll 2
  for (int l = 0; l < CL; l++, t++) {
    float dtv = dt[t * DINNER + d];
    float dx = dtv * bf2f(xs[t * DINNER + d]);
    const float4* Bp = (const float4*)(bc + t * 32);
    const float4* Cp = (const float4*)(bc + t * 32 + 16);
    float4 b0 = Bp[0], b1 = Bp[1], b2 = Bp[2], b3 = Bp[3];
    float4 c0 = Cp[0], c1 = Cp[1], c2 = Cp[2], c3 = Cp[3];
    float bb[DSTATE] = {b0.x, b0.y, b0.z, b0.w, b1.x, b1.y, b1.z, b1.w,
                        b2.x, b2.y, b2.z, b2.w, b3.x, b3.y, b3.z, b3.w};
    float cc[DSTATE] = {c0.x, c0.y, c0.z, c0.w, c1.x, c1.y, c1.z, c1.w,
                        c2.x, c2.y, c2.z, c2.w, c3.x, c3.y, c3.z, c3.w};
    float ysum = 0.f;
#pragma unroll
    for (int n = 0; n < DSTATE; n++) {
      h[n] = __expf(a[n] * dtv) * h[n] + dx * bb[n];
      ysum = fmaf(h[n], cc[n], ysum);
    }
    y[t * DINNER + d] = f2bf(ysum * bf2f(gate[t * DINNER + d]));
  }
}

extern "C" void kernel_launch(void* const* d_in, const int* in_sizes, int n_in,
                              void* d_out, int out_size, void* d_ws, size_t ws_size,
                              hipStream_t stream) {
  const float* x      = (const float*)d_in[0];
  const float* rms_w  = (const float*)d_in[1];
  const float* W_in   = (const float*)d_in[2];
  const float* conv_w = (const float*)d_in[3];
  const float* conv_b = (const float*)d_in[4];
  const float* W_x    = (const float*)d_in[5];
  const float* W_dt   = (const float*)d_in[6];
  const float* A_log  = (const float*)d_in[7];
  const float* W_out  = (const float*)d_in[8];
  float* out = (float*)d_out;

  // workspace layout, byte offsets (total 92,536,832 B)
  char* w = (char*)d_ws;
  ushort* xnb   = (ushort*)(w + 0);         //  4 MiB  bf16 xn (dead after GEMM1)
  ushort* xsraw = (ushort*)(w + 4194304);   //  8 MiB  bf16 (dead after conv)
  ushort* gate  = (ushort*)(w + 12582912);  //  8 MiB  silu(res) bf16 (dead after chunk2)
  ushort* xsb   = (ushort*)(w + 20971520);  //  8 MiB  conv+silu out bf16
  ushort* ssmb  = (ushort*)(w + 29360128);  //  8.125 MiB [2048,2080] bf16
  float*  dtb   = (float*)(w + 37879808);   // 16 MiB  softplus(dt) fp32
  ushort* yb    = (ushort*)(w + 54657024);  //  8 MiB  scan out bf16
  ushort* WinT  = (ushort*)(w + 63045632);  //  8 MiB  (dead after GEMM1)
  ushort* WxT   = (ushort*)(w + 71434240);  //  8.125 MiB (dead after GEMM2)
  ushort* WdtT  = (ushort*)(w + 79953920);  //  8 MiB  (dead after GEMM3)
  ushort* WoutT = (ushort*)(w + 88342528);  //  4 MiB
  // overlays of dead regions:
  float* bc = (float*)(w + 0);          // [2048,32] fp32 B|C (over xnb) — GEMM2 writes
  float* Bc = (float*)(w + 63045632);   // [NC,NCH,16] fp32 = 16 MiB over WinT+WxT (chunk1 after GEMM2)
  float* S  = (float*)(w + 79953920);   // [NC,NCH] fp32 = 1 MiB over WdtT (after GEMM3)
  float* P  = (float*)(w + 4194304);    // [2][2048,1024] fp32 = 16 MiB over xsraw+gate (after chunk2)

  transpose_all<<<3616, 256, 0, stream>>>(W_in, WinT, W_x, WxT, W_dt, WdtT, W_out, WoutT);

  rmsnorm_kernel<<<NTOK, 256, 0, stream>>>(x, rms_w, xnb);
  // xr = xn @ W_in : split -> xsraw (bf16), gate = silu(res) (bf16)
  gemm_mfma<<<dim3(64, 16), 256, 0, stream>>>(
      xnb, DMODEL, WinT, DMODEL, 4096, DMODEL, 1, xsraw, gate, nullptr);
  conv_silu_kernel<<<(NTOK * DINNER) / 256, 256, 0, stream>>>(xsraw, conv_w, conv_b, xsb);
  // ssm = xs @ W_x : bf16 full + fp32 B/C columns compact
  gemm_mfma<<<dim3(33, 16), 256, 0, stream>>>(
      xsb, DINNER, WxT, DINNER, NSSM, DINNER, 2, ssmb, bc, nullptr);
  // dt = softplus(ssm[:, :2048] @ W_dt) fp32
  gemm_mfma<<<dim3(32, 16), 256, 0, stream>>>(
      ssmb, NSSM, WdtT, DINNER, DINNER, DINNER, 3, dtb, nullptr, nullptr);
  // chunked scan
  scan_chunk1<<<B_SZ * NCH * 8, 256, 0, stream>>>(dtb, xsb, bc, A_log, Bc, S);
  scan_combine<<<(NC * DSTATE) / 256, 256, 0, stream>>>(A_log, S, Bc);
  scan_chunk2<<<B_SZ * NCH * 8, 256, 0, stream>>>(dtb, xsb, bc, gate, A_log, Bc, yb);
  // out = y @ W_out + x : split-K x2 (z = K-slice) then reduce+residual
  gemm_mfma<<<dim3(16, 16, 2), 256, 0, stream>>>(
      yb, DINNER, WoutT, DINNER, DMODEL, DINNER / 2, 0, P, nullptr, nullptr);
  reduce_wout<<<(NTOK * DMODEL / 4) / 256, 256, 0, stream>>>(P, x, out);
}